// Round 1
// baseline (2432.914 us; speedup 1.0000x reference)
//
#include <hip/hip_runtime.h>
#include <cstdint>

typedef __bf16 bf16_t;
typedef __bf16 bf16x8 __attribute__((ext_vector_type(8)));
typedef __bf16 bf16x4 __attribute__((ext_vector_type(4)));
typedef float f32x4 __attribute__((ext_vector_type(4)));

#define NTOK 4096
#define DIM 768
#define DEPTH 6
#define HEADS 12
#define DHD 64
#define FFD 3072
#define MFEAT 256
#define VOUT 102

// ---------------- async global->LDS (16B per lane, wave-uniform LDS base) -------------
__device__ __forceinline__ void gl_lds16(const void* g, void* l) {
    __builtin_amdgcn_global_load_lds(
        (__attribute__((address_space(1))) void*)(g),
        (__attribute__((address_space(3))) void*)(l), 16, 0, 0);
}

// ---------------- MFMA GEMM: C[M,N] = A[M,K] @ B^T[N,K]  (A,B bf16 row-major with ld) --
// MODE 0: f32 out = dot
// MODE 1: f32 out += dot + bias[col]        (residual accumulate)
// MODE 2: bf16 out = gelu(dot + bias[col])
// MODE 3: bf16 out = dot * rowscale[row], col < Nvalid
// MODE 4: atomicAdd f32 out += dot, row < Mvalid   (split-K)
// MODE 5: f32 out = dot + bias[col], col < Nvalid
template<int MODE>
__global__ __launch_bounds__(256, 2) void gemm128(
    const bf16_t* __restrict__ A, int lda, long sA,
    const bf16_t* __restrict__ B, int ldb, long sB,
    void* __restrict__ Cout, int ldc, long sC,
    int K, int nsplit,
    const float* __restrict__ bias,
    const float* __restrict__ rowscale, int sRS,
    int Mvalid, int Nvalid)
{
    __shared__ __align__(16) bf16_t As[128 * 64];
    __shared__ __align__(16) bf16_t Bs[128 * 64];
    const int bz = blockIdx.z;
    const int batch = bz / nsplit, chunk = bz % nsplit;
    A += (long)batch * sA;
    B += (long)batch * sB;
    const int t = threadIdx.x;
    const int wave = t >> 6, lane = t & 63;
    const int wm = wave >> 1, wn = wave & 1;
    const int q = lane >> 4, r = lane & 15;
    const int tileM = blockIdx.x * 128, tileN = blockIdx.y * 128;
    const int Kc = K / nsplit;
    const int k0 = chunk * Kc;

    f32x4 acc[4][4] = {};

    for (int kt = 0; kt < Kc; kt += 64) {
        const int kb = k0 + kt;
#pragma unroll
        for (int i = 0; i < 4; i++) {
            const int c = i * 256 + t;
            const int row = c >> 3, kk = (c & 7) * 8;
            const bf16_t* ga = A + (long)(tileM + row) * lda + kb + kk;
            const bf16_t* gb = B + (long)(tileN + row) * ldb + kb + kk;
            char* la = (char*)As + (i * 256 + wave * 64) * 16;   // wave-uniform base
            char* lb = (char*)Bs + (i * 256 + wave * 64) * 16;
            gl_lds16(ga, la);
            gl_lds16(gb, lb);
        }
        __syncthreads();
#pragma unroll
        for (int kk = 0; kk < 64; kk += 32) {
            bf16x8 af[4], bfr[4];
#pragma unroll
            for (int i = 0; i < 4; i++) {
                const int m = wm * 64 + i * 16 + r;
                af[i] = *(const bf16x8*)(As + m * 64 + kk + q * 8);
            }
#pragma unroll
            for (int j = 0; j < 4; j++) {
                const int n = wn * 64 + j * 16 + r;
                bfr[j] = *(const bf16x8*)(Bs + n * 64 + kk + q * 8);
            }
#pragma unroll
            for (int i = 0; i < 4; i++)
#pragma unroll
                for (int j = 0; j < 4; j++)
                    acc[i][j] = __builtin_amdgcn_mfma_f32_16x16x32_bf16(af[i], bfr[j], acc[i][j], 0, 0, 0);
        }
        __syncthreads();
    }

    // C/D layout: col = lane&15 (=r), row-in-tile = q*4 + e
#pragma unroll
    for (int i = 0; i < 4; i++) {
#pragma unroll
        for (int j = 0; j < 4; j++) {
#pragma unroll
            for (int e = 0; e < 4; e++) {
                const int R = tileM + wm * 64 + i * 16 + q * 4 + e;
                const int Cc = tileN + wn * 64 + j * 16 + r;
                const float v = acc[i][j][e];
                if (MODE == 0) {
                    float* C = (float*)Cout + (long)batch * sC;
                    C[(long)R * ldc + Cc] = v;
                } else if (MODE == 1) {
                    float* C = (float*)Cout;
                    C[(long)R * ldc + Cc] += v + bias[Cc];
                } else if (MODE == 2) {
                    const float x = v + bias[Cc];
                    const float z = 0.7978845608028654f * (x + 0.044715f * x * x * x);
                    const float th = 1.0f - 2.0f / (__expf(2.0f * z) + 1.0f);
                    bf16_t* Gp = (bf16_t*)Cout;
                    Gp[(long)R * ldc + Cc] = (bf16_t)(0.5f * x * (1.0f + th));
                } else if (MODE == 3) {
                    if (Cc < Nvalid) {
                        const float* rs = rowscale + (long)batch * sRS;
                        bf16_t* Ob = (bf16_t*)Cout + (long)batch * sC;
                        Ob[(long)R * ldc + Cc] = (bf16_t)(v * rs[R]);
                    }
                } else if (MODE == 4) {
                    if (R < Mvalid) {
                        float* C = (float*)Cout + (long)batch * sC;
                        atomicAdd(&C[(long)R * ldc + Cc], v);
                    }
                } else if (MODE == 5) {
                    if (Cc < Nvalid) {
                        float* C = (float*)Cout;
                        C[(long)R * ldc + Cc] = v + bias[Cc];
                    }
                }
            }
        }
    }
}

// ---------------- bucketize (searchsorted left) + mask ----------------
__global__ void bucket_kernel(const float* __restrict__ methy, int* __restrict__ idx, float* __restrict__ maskf) {
    const int n = blockIdx.x * 256 + threadIdx.x;
    if (n >= NTOK) return;
    const float u = methy[n];
    int cnt = (int)(u > -2.0f) + (int)(u > -1.0f);
    for (int k = 0; k < 100; k++) cnt += (int)(((float)k * 0.01f) < u);
    idx[n] = cnt;
    maskf[n] = (u != 0.0f) ? 1.0f : 0.0f;
}

// ---------------- embedding gather ----------------
__global__ void embed_kernel(const int* __restrict__ idx, const int* __restrict__ pos, const int* __restrict__ chromo,
                             const float* __restrict__ mt, const float* __restrict__ pt, const float* __restrict__ ct,
                             float* __restrict__ X) {
    const int n = blockIdx.x, t = threadIdx.x;  // 192 threads * float4
    const float4* a = (const float4*)(mt + (long)idx[n] * DIM);
    const float4* b = (const float4*)(pt + (long)pos[n] * DIM);
    const float4* c = (const float4*)(ct + (long)chromo[n] * DIM);
    float4 rr = a[t];
    const float4 u = b[t], w = c[t];
    rr.x += u.x + w.x; rr.y += u.y + w.y; rr.z += u.z + w.z; rr.w += u.w + w.w;
    ((float4*)(X + (long)n * DIM))[t] = rr;
}

// ---------------- layernorm -> bf16 ----------------
__global__ __launch_bounds__(256) void ln_kernel(const float* __restrict__ X,
        const float* __restrict__ g, const float* __restrict__ b, bf16_t* __restrict__ out) {
    const int n = blockIdx.x, t = threadIdx.x;
    const float* x = X + (long)n * DIM;
    const float v0 = x[t], v1 = x[t + 256], v2 = x[t + 512];
    float s = v0 + v1 + v2;
    float s2 = v0 * v0 + v1 * v1 + v2 * v2;
    __shared__ float smA[4], smB[4];
    for (int o = 32; o; o >>= 1) { s += __shfl_down(s, o); s2 += __shfl_down(s2, o); }
    if ((t & 63) == 0) { smA[t >> 6] = s; smB[t >> 6] = s2; }
    __syncthreads();
    s = smA[0] + smA[1] + smA[2] + smA[3];
    s2 = smB[0] + smB[1] + smB[2] + smB[3];
    const float mu = s * (1.0f / DIM);
    const float var = s2 * (1.0f / DIM) - mu * mu;
    const float rs = rsqrtf(var + 1e-5f);
    bf16_t* op = out + (long)n * DIM;
    op[t]       = (bf16_t)((v0 - mu) * rs * g[t]       + b[t]);
    op[t + 256] = (bf16_t)((v1 - mu) * rs * g[t + 256] + b[t + 256]);
    op[t + 512] = (bf16_t)((v2 - mu) * rs * g[t + 512] + b[t + 512]);
}

// ---------------- f32 [R,C] -> bf16 [C,R] transpose (guarded) ----------------
__global__ __launch_bounds__(256) void transpose_kernel(const float* __restrict__ in, int R, int C,
                                                        bf16_t* __restrict__ out, int ldo) {
    __shared__ float tile[32][33];
    const int c0 = blockIdx.x * 32, r0 = blockIdx.y * 32;
    const int t = threadIdx.x;
    const int tx = t & 31, ty = t >> 5;
    for (int i = 0; i < 32; i += 8) {
        const int rr = r0 + ty + i, cc = c0 + tx;
        tile[ty + i][tx] = (rr < R && cc < C) ? in[(long)rr * C + cc] : 0.0f;
    }
    __syncthreads();
    for (int i = 0; i < 32; i += 8) {
        const int cc = c0 + ty + i, rr = r0 + tx;
        if (cc < C && rr < R) out[(long)cc * ldo + rr] = (bf16_t)tile[tx][ty + i];
    }
}

// ---------------- generic f32 -> bf16 convert ----------------
__global__ void conv_kernel(const float* __restrict__ in, bf16_t* __restrict__ out, long n) {
    const long i = ((long)blockIdx.x * 256 + threadIdx.x) * 4;
    if (i >= n) return;
    const float4 v = *(const float4*)(in + i);
    bf16x4 o; o[0] = (bf16_t)v.x; o[1] = (bf16_t)v.y; o[2] = (bf16_t)v.z; o[3] = (bf16_t)v.w;
    *(bf16x4*)(out + i) = o;
}

// ---------------- Cqkv q,k columns -> bf16 * dnorm ----------------
__global__ void qkconv_kernel(const float* __restrict__ C, bf16_t* __restrict__ out) {
    const long i = ((long)blockIdx.x * 256 + threadIdx.x) * 4;
    const int n = (int)(i / 1536), c = (int)(i % 1536);
    const float4 v = *(const float4*)(C + (long)n * 2304 + c);
    const float dn = 0.3535533905932738f;  // 64^-0.25
    bf16x4 o; o[0] = (bf16_t)(v.x * dn); o[1] = (bf16_t)(v.y * dn); o[2] = (bf16_t)(v.z * dn); o[3] = (bf16_t)(v.w * dn);
    *(bf16x4*)(out + i) = o;
}

// ---------------- V columns -> VT[h][d][n] bf16 (rows 64..127 pre-zeroed) ----------------
__global__ __launch_bounds__(256) void vt_kernel(const float* __restrict__ Cqkv, bf16_t* __restrict__ VT) {
    const int h = blockIdx.y, n0 = blockIdx.x * 32;
    __shared__ float tile[64][33];
    const int t = threadIdx.x;
    const int d = t & 63, nl = t >> 6;
    for (int i = 0; i < 32; i += 4)
        tile[d][nl + i] = Cqkv[(long)(n0 + nl + i) * 2304 + 1536 + h * 64 + d];
    __syncthreads();
    const int n2 = t & 31, d2 = t >> 5;
    for (int i = 0; i < 64; i += 8)
        VT[((long)h * 128 + d2 + i) * 4096 + n0 + n2] = (bf16_t)tile[d2 + i][n2];
}

// ---------------- diag = 0.5*||xn||^2 for q and k ----------------
__global__ __launch_bounds__(256) void diag_kernel(const bf16_t* __restrict__ QKbf,
                                                   float* __restrict__ diagQ, float* __restrict__ diagK) {
    const int h = blockIdx.y;
    const int n = blockIdx.x * 4 + (threadIdx.x >> 6);
    const int lane = threadIdx.x & 63;
    const float qv = (float)QKbf[(long)n * 1536 + h * 64 + lane];
    const float kv = (float)QKbf[(long)n * 1536 + 768 + h * 64 + lane];
    float sq = qv * qv, sk = kv * kv;
    for (int o = 32; o; o >>= 1) { sq += __shfl_down(sq, o); sk += __shfl_down(sk, o); }
    if (lane == 0) { diagQ[h * 4096 + n] = 0.5f * sq; diagK[h * 4096 + n] = 0.5f * sk; }
}

// ---------------- qf = ratio*(exp(xd - diag - rowmax) + eps), bf16 ----------------
__global__ __launch_bounds__(256) void qf_kernel(const float* __restrict__ XD, const float* __restrict__ diagQ,
                                                 bf16_t* __restrict__ QF) {
    const int h = blockIdx.y;
    const int n = blockIdx.x * 4 + (threadIdx.x >> 6);
    const int lane = threadIdx.x & 63;
    const float4 v = *(const float4*)(XD + ((long)h * 4096 + n) * 256 + lane * 4);
    float mx = fmaxf(fmaxf(v.x, v.y), fmaxf(v.z, v.w));
    for (int o = 32; o; o >>= 1) mx = fmaxf(mx, __shfl_down(mx, o));
    mx = __shfl(mx, 0);
    const float dg = diagQ[h * 4096 + n] + mx;
    const float ratio = 0.0625f;
    bf16x4 ov;
    ov[0] = (bf16_t)(ratio * (__expf(v.x - dg) + 1e-4f));
    ov[1] = (bf16_t)(ratio * (__expf(v.y - dg) + 1e-4f));
    ov[2] = (bf16_t)(ratio * (__expf(v.z - dg) + 1e-4f));
    ov[3] = (bf16_t)(ratio * (__expf(v.w - dg) + 1e-4f));
    *(bf16x4*)(QF + ((long)h * 4096 + n) * 256 + lane * 4) = ov;
}

// ---------------- per-head global max over xd_k ----------------
__global__ __launch_bounds__(256) void kmax1_kernel(const float* __restrict__ XD, float* __restrict__ part) {
    const int h = blockIdx.y;
    const float* pp = XD + (long)h * 1048576 + (long)blockIdx.x * 32768;
    float m = -3.0e38f;
    for (int i = threadIdx.x; i < 32768; i += 256) m = fmaxf(m, pp[i]);
    for (int o = 32; o; o >>= 1) m = fmaxf(m, __shfl_down(m, o));
    __shared__ float sm[4];
    if ((threadIdx.x & 63) == 0) sm[threadIdx.x >> 6] = m;
    __syncthreads();
    if (threadIdx.x == 0) part[h * 32 + blockIdx.x] = fmaxf(fmaxf(sm[0], sm[1]), fmaxf(sm[2], sm[3]));
}
__global__ void kmax2_kernel(const float* __restrict__ part, float* __restrict__ kmx) {
    const int h = blockIdx.x;
    float m = (threadIdx.x < 32) ? part[h * 32 + threadIdx.x] : -3.0e38f;
    for (int o = 32; o; o >>= 1) m = fmaxf(m, __shfl_down(m, o));
    if (threadIdx.x == 0) kmx[h] = m;
}

// ---------------- kf -> KFT[h][m][n] bf16 (+ksum atomics) ----------------
__global__ __launch_bounds__(256) void kft_kernel(const float* __restrict__ XD, const float* __restrict__ diagK,
        const float* __restrict__ kmx, const float* __restrict__ maskf,
        bf16_t* __restrict__ KFT, float* __restrict__ ksum) {
    const int h = blockIdx.z, n0 = blockIdx.x * 128, m0 = blockIdx.y * 64;
    __shared__ bf16_t tile[64][136];
    const int t = threadIdx.x;
    const int ml = (t & 15) * 4, nl = t >> 4;
    const float km = kmx[h];
    const float ratio = 0.0625f;
    for (int i = 0; i < 128; i += 16) {
        const int n = n0 + nl + i;
        const float4 v = *(const float4*)(XD + ((long)h * 4096 + n) * 256 + m0 + ml);
        const float e = diagK[h * 4096 + n] + km;
        const float msk = maskf[n];
        tile[ml + 0][nl + i] = (bf16_t)(ratio * (__expf(v.x - e) + 1e-4f) * msk);
        tile[ml + 1][nl + i] = (bf16_t)(ratio * (__expf(v.y - e) + 1e-4f) * msk);
        tile[ml + 2][nl + i] = (bf16_t)(ratio * (__expf(v.z - e) + 1e-4f) * msk);
        tile[ml + 3][nl + i] = (bf16_t)(ratio * (__expf(v.w - e) + 1e-4f) * msk);
    }
    __syncthreads();
    const int nc = t & 127, mc = t >> 7;
    for (int i = 0; i < 64; i += 2) {
        const int m = i + mc;
        KFT[((long)h * 256 + m0 + m) * 4096 + n0 + nc] = tile[m][nc];
    }
    if (t < 64) {
        float s = 0.0f;
        for (int nn = 0; nn < 128; nn++) s += (float)tile[t][nn];
        atomicAdd(&ksum[h * 256 + m0 + t], s);
    }
}

// ---------------- d_inv = 1 / (qf . ksum) ----------------
__global__ __launch_bounds__(256) void denom_kernel(const bf16_t* __restrict__ QF, const float* __restrict__ ksum,
                                                    float* __restrict__ dinv) {
    const int h = blockIdx.y;
    const int n = blockIdx.x * 4 + (threadIdx.x >> 6);
    const int lane = threadIdx.x & 63;
    const bf16x4 qv = *(const bf16x4*)(QF + ((long)h * 4096 + n) * 256 + lane * 4);
    const float4 ks = *(const float4*)(ksum + h * 256 + lane * 4);
    float s = (float)qv[0] * ks.x + (float)qv[1] * ks.y + (float)qv[2] * ks.z + (float)qv[3] * ks.w;
    for (int o = 32; o; o >>= 1) s += __shfl_down(s, o);
    if (lane == 0) dinv[h * 4096 + n] = 1.0f / s;
}

// ---------------- ctx f32 [12][64][256] -> bf16 [12][128][256] (pad rows zeroed) ------
__global__ void ctxconv_kernel(const float* __restrict__ in, bf16_t* __restrict__ out) {
    const long i = ((long)blockIdx.x * 256 + threadIdx.x) * 4;
    const int h = (int)(i >> 14);
    const int rem = (int)(i & 16383);
    const float4 v = *(const float4*)(in + i);
    bf16x4 o; o[0] = (bf16_t)v.x; o[1] = (bf16_t)v.y; o[2] = (bf16_t)v.z; o[3] = (bf16_t)v.w;
    *(bf16x4*)(out + (long)h * 32768 + rem) = o;
}

extern "C" void kernel_launch(void* const* d_in, const int* in_sizes, int n_in,
                              void* d_out, int out_size, void* d_ws, size_t ws_size,
                              hipStream_t stream) {
    const float* methy        = (const float*)d_in[0];
    const int*   chromo       = (const int*)d_in[1];
    const int*   pos          = (const int*)d_in[2];
    const float* methy_table  = (const float*)d_in[3];
    const float* chromo_table = (const float*)d_in[4];
    const float* pos_table    = (const float*)d_in[5];
    const float* ln1_g = (const float*)d_in[6];
    const float* ln1_b = (const float*)d_in[7];
    const float* ln2_g = (const float*)d_in[8];
    const float* ln2_b = (const float*)d_in[9];
    const float* Wq = (const float*)d_in[10];
    const float* Wk = (const float*)d_in[11];
    const float* Wv = (const float*)d_in[12];
    const float* Wo = (const float*)d_in[13];
    const float* bo = (const float*)d_in[14];
    const float* W1 = (const float*)d_in[15];
    const float* b1 = (const float*)d_in[16];
    const float* W2 = (const float*)d_in[17];
    const float* b2 = (const float*)d_in[18];
    const float* proj = (const float*)d_in[19];
    const float* normf_g = (const float*)d_in[20];
    const float* normf_b = (const float*)d_in[21];
    const float* Wout = (const float*)d_in[22];
    const float* bout = (const float*)d_in[23];

    char* p = (char*)d_ws;
    auto alloc = [&](size_t bytes) { char* r = p; p += (bytes + 255) & ~(size_t)255; return r; };

    float*  X     = (float*)alloc((size_t)NTOK * DIM * 4);
    bf16_t* Hbf   = (bf16_t*)alloc((size_t)NTOK * DIM * 2);
    char*   BIG   = alloc((size_t)12 * 4096 * 256 * 4);   // Cqkv(f32) / XD(f32) / G(bf16)
    float*  Cqkv  = (float*)BIG;
    float*  XD    = (float*)BIG;
    bf16_t* G     = (bf16_t*)BIG;
    bf16_t* QKbf  = (bf16_t*)alloc((size_t)NTOK * 1536 * 2);  // also reused as O (attn out, bf16)
    bf16_t* O     = QKbf;
    bf16_t* VT    = (bf16_t*)alloc((size_t)12 * 128 * 4096 * 2);
    bf16_t* QF    = (bf16_t*)alloc((size_t)12 * 4096 * 256 * 2);
    bf16_t* KFT   = (bf16_t*)alloc((size_t)12 * 256 * 4096 * 2);
    bf16_t* WqkvT = (bf16_t*)alloc((size_t)2304 * 768 * 2);
    bf16_t* WoT   = (bf16_t*)alloc((size_t)768 * 768 * 2);
    bf16_t* W1T   = (bf16_t*)alloc((size_t)3072 * 768 * 2);
    bf16_t* W2T   = (bf16_t*)alloc((size_t)768 * 3072 * 2);
    bf16_t* projbf= (bf16_t*)alloc((size_t)256 * 64 * 2);
    bf16_t* WoutT = (bf16_t*)alloc((size_t)128 * 768 * 2);
    float*  CTXf  = (float*)alloc((size_t)12 * 64 * 256 * 4);
    bf16_t* CTXbf = (bf16_t*)alloc((size_t)12 * 128 * 256 * 2);
    float*  diagQ = (float*)alloc((size_t)12 * 4096 * 4);
    float*  diagK = (float*)alloc((size_t)12 * 4096 * 4);
    float*  DINV  = (float*)alloc((size_t)12 * 4096 * 4);
    float*  ksum  = (float*)alloc((size_t)12 * 256 * 4);
    float*  kmaxp = (float*)alloc((size_t)12 * 32 * 4);
    float*  kmx   = (float*)alloc(256);
    int*    idxb  = (int*)alloc((size_t)4096 * 4);
    float*  maskf = (float*)alloc((size_t)4096 * 4);

    hipMemsetAsync(VT, 0, (size_t)12 * 128 * 4096 * 2, stream);
    hipMemsetAsync(CTXbf, 0, (size_t)12 * 128 * 256 * 2, stream);
    hipMemsetAsync(WoutT, 0, (size_t)128 * 768 * 2, stream);

    bucket_kernel<<<16, 256, 0, stream>>>(methy, idxb, maskf);
    embed_kernel<<<4096, 192, 0, stream>>>(idxb, pos, chromo, methy_table, pos_table, chromo_table, X);
    transpose_kernel<<<dim3(4, 24), 256, 0, stream>>>(Wout, 768, VOUT, WoutT, 768);

    for (int l = 0; l < DEPTH; l++) {
        const long w768 = (long)l * 768 * 768;
        transpose_kernel<<<dim3(24, 24), 256, 0, stream>>>(Wq + w768, 768, 768, WqkvT, 768);
        transpose_kernel<<<dim3(24, 24), 256, 0, stream>>>(Wk + w768, 768, 768, WqkvT + 768 * 768, 768);
        transpose_kernel<<<dim3(24, 24), 256, 0, stream>>>(Wv + w768, 768, 768, WqkvT + 2 * 768 * 768, 768);
        transpose_kernel<<<dim3(24, 24), 256, 0, stream>>>(Wo + w768, 768, 768, WoT, 768);
        transpose_kernel<<<dim3(96, 24), 256, 0, stream>>>(W1 + (long)l * 768 * 3072, 768, 3072, W1T, 768);
        transpose_kernel<<<dim3(24, 96), 256, 0, stream>>>(W2 + (long)l * 3072 * 768, 3072, 768, W2T, 3072);
        conv_kernel<<<16, 256, 0, stream>>>(proj + (long)l * 256 * 64, projbf, 256 * 64);

        // x -> LN1 -> Hbf ; QKV
        ln_kernel<<<4096, 256, 0, stream>>>(X, ln1_g + l * DIM, ln1_b + l * DIM, Hbf);
        gemm128<0><<<dim3(32, 18, 1), 256, 0, stream>>>(Hbf, 768, 0, WqkvT, 768, 0, Cqkv, 2304, 0,
                                                        768, 1, nullptr, nullptr, 0, 4096, 2304);
        qkconv_kernel<<<6144, 256, 0, stream>>>(Cqkv, QKbf);
        vt_kernel<<<dim3(128, 12), 256, 0, stream>>>(Cqkv, VT);
        diag_kernel<<<dim3(1024, 12), 256, 0, stream>>>(QKbf, diagQ, diagK);

        // q features
        gemm128<0><<<dim3(32, 2, 12), 256, 0, stream>>>(QKbf, 1536, 64, projbf, 64, 0, XD, 256, 1048576,
                                                        64, 1, nullptr, nullptr, 0, 4096, 256);
        qf_kernel<<<dim3(1024, 12), 256, 0, stream>>>(XD, diagQ, QF);

        // k features (global max -> exp -> transposed store + ksum)
        gemm128<0><<<dim3(32, 2, 12), 256, 0, stream>>>(QKbf + 768, 1536, 64, projbf, 64, 0, XD, 256, 1048576,
                                                        64, 1, nullptr, nullptr, 0, 4096, 256);
        kmax1_kernel<<<dim3(32, 12), 256, 0, stream>>>(XD, kmaxp);
        kmax2_kernel<<<12, 64, 0, stream>>>(kmaxp, kmx);
        hipMemsetAsync(ksum, 0, (size_t)12 * 256 * 4, stream);
        hipMemsetAsync(CTXf, 0, (size_t)12 * 64 * 256 * 4, stream);
        kft_kernel<<<dim3(32, 4, 12), 256, 0, stream>>>(XD, diagK, kmx, maskf, KFT, ksum);
        denom_kernel<<<dim3(1024, 12), 256, 0, stream>>>(QF, ksum, DINV);

        // ctx^T[h][d][m] = sum_n v[n][d] kf[n][m]   (split-K over n, atomic f32)
        gemm128<4><<<dim3(1, 2, 96), 256, 0, stream>>>(VT, 4096, (long)128 * 4096, KFT, 4096, (long)256 * 4096,
                                                       CTXf, 256, (long)64 * 256, 4096, 8,
                                                       nullptr, nullptr, 0, 64, 256);
        ctxconv_kernel<<<192, 256, 0, stream>>>(CTXf, CTXbf);

        // o[n][h*64+d] = dinv[h][n] * sum_m qf[n][m] ctx^T[d][m]
        gemm128<3><<<dim3(32, 1, 12), 256, 0, stream>>>(QF, 256, (long)4096 * 256, CTXbf, 256, (long)128 * 256,
                                                        O, 768, 64, 256, 1, nullptr, DINV, 4096, 4096, 64);
        // x += o @ Wo + bo
        gemm128<1><<<dim3(32, 6, 1), 256, 0, stream>>>(O, 768, 0, WoT, 768, 0, X, 768, 0,
                                                       768, 1, bo + l * DIM, nullptr, 0, 4096, 768);
        // FF
        ln_kernel<<<4096, 256, 0, stream>>>(X, ln2_g + l * DIM, ln2_b + l * DIM, Hbf);
        gemm128<2><<<dim3(32, 24, 1), 256, 0, stream>>>(Hbf, 768, 0, W1T, 768, 0, G, 3072, 0,
                                                        768, 1, b1 + l * FFD, nullptr, 0, 4096, 3072);
        gemm128<1><<<dim3(32, 6, 1), 256, 0, stream>>>(G, 3072, 0, W2T, 3072, 0, X, 768, 0,
                                                       3072, 1, b2 + l * DIM, nullptr, 0, 4096, 768);
    }

    ln_kernel<<<4096, 256, 0, stream>>>(X, normf_g, normf_b, Hbf);
    gemm128<5><<<dim3(32, 1, 1), 256, 0, stream>>>(Hbf, 768, 0, WoutT, 768, 0, d_out, VOUT, 0,
                                                   768, 1, bout, nullptr, 0, 4096, VOUT);
}

// Round 2
// 2158.348 us; speedup vs baseline: 1.1272x; 1.1272x over previous
//
#include <hip/hip_runtime.h>
#include <cstdint>

typedef __bf16 bf16_t;
typedef __bf16 bf16x8 __attribute__((ext_vector_type(8)));
typedef __bf16 bf16x4 __attribute__((ext_vector_type(4)));
typedef float f32x4 __attribute__((ext_vector_type(4)));

#define NTOK 4096
#define DIM 768
#define DEPTH 6
#define HEADS 12
#define FFD 3072
#define VOUT 102

// ---------------- async global->LDS (16B per lane, wave-uniform LDS base) -------------
__device__ __forceinline__ void gl_lds16(const void* g, void* l) {
    __builtin_amdgcn_global_load_lds(
        (__attribute__((address_space(1))) void*)(g),
        (__attribute__((address_space(3))) void*)(l), 16, 0, 0);
}

__device__ __forceinline__ unsigned enc_f32(float f) {
    unsigned u = __float_as_uint(f);
    return (u & 0x80000000u) ? ~u : (u | 0x80000000u);
}
__device__ __forceinline__ float dec_f32(unsigned e) {
    unsigned u = (e & 0x80000000u) ? (e & 0x7FFFFFFFu) : ~e;
    return __uint_as_float(u);
}

// ---------------- MFMA GEMM: C[M,N] = A[M,K] @ B^T[N,K]  (A,B bf16 row-major) ---------
// MODE 0: f32 out = dot
// MODE 2: bf16 out = gelu(dot + bias[col])
// MODE 3: bf16 out = dot * rowscale[row], col < Nvalid
// MODE 4: atomicAdd f32 out += dot, row < Mvalid   (split-K)
// MODE 5: f32 out = dot + bias[col], col < Nvalid
// MODE 6: f32 out = dot; per-head global max -> atomicMax(aux[batch]) (encoded)
// MODE 7: atomicAdd f32 out += dot + (chunk==0 ? bias[col] : 0)   (split-K residual)
// MODE 8: fused QKV epilogue: q/k tiles -> QKbf(bf16*dn) + diagQ/diagK(bias/rowscale);
//         v tiles -> VT[h][d][n] via LDS transpose (aux)
template<int MODE>
__global__ __launch_bounds__(256, 2) void gemm128(
    const bf16_t* __restrict__ A, int lda, long sA,
    const bf16_t* __restrict__ B, int ldb, long sB,
    void* __restrict__ Cout, int ldc, long sC,
    int K, int nsplit,
    const float* __restrict__ bias,
    const float* __restrict__ rowscale, int sRS,
    int Mvalid, int Nvalid, void* __restrict__ aux)
{
    __shared__ __align__(16) bf16_t smem[16896];   // As(8192) + Bs(8192); reused 128x130 in MODE 8
    bf16_t* As = smem;
    bf16_t* Bs = smem + 8192;
    const int bz = blockIdx.z;
    const int batch = bz / nsplit, chunk = bz % nsplit;
    A += (long)batch * sA;
    B += (long)batch * sB;
    const int t = threadIdx.x;
    const int wave = t >> 6, lane = t & 63;
    const int wm = wave >> 1, wn = wave & 1;
    const int q = lane >> 4, r = lane & 15;
    const int tileM = blockIdx.x * 128, tileN = blockIdx.y * 128;
    const int Kc = K / nsplit;
    const int k0 = chunk * Kc;

    f32x4 acc[4][4] = {};

    for (int kt = 0; kt < Kc; kt += 64) {
        const int kb = k0 + kt;
#pragma unroll
        for (int i = 0; i < 4; i++) {
            const int c = i * 256 + t;
            const int row = c >> 3, kk = (c & 7) * 8;
            const bf16_t* ga = A + (long)(tileM + row) * lda + kb + kk;
            const bf16_t* gb = B + (long)(tileN + row) * ldb + kb + kk;
            char* la = (char*)As + (i * 256 + wave * 64) * 16;   // wave-uniform base
            char* lb = (char*)Bs + (i * 256 + wave * 64) * 16;
            gl_lds16(ga, la);
            gl_lds16(gb, lb);
        }
        __syncthreads();
#pragma unroll
        for (int kk = 0; kk < 64; kk += 32) {
            bf16x8 af[4], bfr[4];
#pragma unroll
            for (int i = 0; i < 4; i++)
                af[i] = *(const bf16x8*)(As + (wm * 64 + i * 16 + r) * 64 + kk + q * 8);
#pragma unroll
            for (int j = 0; j < 4; j++)
                bfr[j] = *(const bf16x8*)(Bs + (wn * 64 + j * 16 + r) * 64 + kk + q * 8);
#pragma unroll
            for (int i = 0; i < 4; i++)
#pragma unroll
                for (int j = 0; j < 4; j++)
                    acc[i][j] = __builtin_amdgcn_mfma_f32_16x16x32_bf16(af[i], bfr[j], acc[i][j], 0, 0, 0);
        }
        __syncthreads();
    }

    // C/D layout: col = lane&15 (=r), row-in-tile = q*4 + e
    if (MODE == 8) {
        const float dn = 0.3535533905932738f;  // 64^-0.25
        if (tileN < 1536) {
            bf16_t* QK = (bf16_t*)Cout;                 // [4096][1536]
            const int hcol = (tileN >> 6) + wn;         // 0..23 (q heads then k heads)
            float* dptr = (hcol < 12) ? ((float*)bias + (long)hcol * 4096)
                                      : ((float*)rowscale + (long)(hcol - 12) * 4096);
#pragma unroll
            for (int i = 0; i < 4; i++) {
#pragma unroll
                for (int e = 0; e < 4; e++) {
                    const int R = tileM + wm * 64 + i * 16 + q * 4 + e;
                    float ss = 0.0f;
#pragma unroll
                    for (int j = 0; j < 4; j++) {
                        const int Cc = tileN + wn * 64 + j * 16 + r;
                        const float v = acc[i][j][e] * dn;
                        QK[(long)R * 1536 + Cc] = (bf16_t)v;
                        ss += v * v;
                    }
                    for (int o = 8; o; o >>= 1) ss += __shfl_xor(ss, o);
                    if (r == 0) dptr[R] = 0.5f * ss;
                }
            }
        } else {
            bf16_t* VTp = (bf16_t*)aux;                 // [12][128][4096]
            bf16_t* tile = smem;                        // [128 cols][130]
#pragma unroll
            for (int i = 0; i < 4; i++)
#pragma unroll
                for (int j = 0; j < 4; j++)
#pragma unroll
                    for (int e = 0; e < 4; e++) {
                        const int row = wm * 64 + i * 16 + q * 4 + e;   // n-local
                        const int col = wn * 64 + j * 16 + r;           // d-local
                        tile[col * 130 + row] = (bf16_t)acc[i][j][e];
                    }
            __syncthreads();
            const int col = t >> 1, half = (t & 1) * 64;
            const int cg = tileN - 1536 + col;          // 0..767
            const int h = cg >> 6, d = cg & 63;
            bf16_t* dst = VTp + ((long)h * 128 + d) * 4096 + tileM + half;
            const bf16_t* src = tile + col * 130 + half;
#pragma unroll
            for (int u2 = 0; u2 < 64; u2 += 8)
                *(bf16x8*)(dst + u2) = *(const bf16x8*)(src + u2);
        }
        return;
    }

    float mymax = -3.0e38f;
#pragma unroll
    for (int i = 0; i < 4; i++) {
#pragma unroll
        for (int j = 0; j < 4; j++) {
#pragma unroll
            for (int e = 0; e < 4; e++) {
                const int R = tileM + wm * 64 + i * 16 + q * 4 + e;
                const int Cc = tileN + wn * 64 + j * 16 + r;
                const float v = acc[i][j][e];
                if (MODE == 0) {
                    float* C = (float*)Cout + (long)batch * sC;
                    C[(long)R * ldc + Cc] = v;
                } else if (MODE == 2) {
                    const float x = v + bias[Cc];
                    const float z = 0.7978845608028654f * (x + 0.044715f * x * x * x);
                    const float th = 1.0f - 2.0f / (__expf(2.0f * z) + 1.0f);
                    bf16_t* Gp = (bf16_t*)Cout;
                    Gp[(long)R * ldc + Cc] = (bf16_t)(0.5f * x * (1.0f + th));
                } else if (MODE == 3) {
                    if (Cc < Nvalid) {
                        const float* rs = rowscale + (long)batch * sRS;
                        bf16_t* Ob = (bf16_t*)Cout + (long)batch * sC;
                        Ob[(long)R * ldc + Cc] = (bf16_t)(v * rs[R]);
                    }
                } else if (MODE == 4) {
                    if (R < Mvalid) {
                        float* C = (float*)Cout + (long)batch * sC;
                        atomicAdd(&C[(long)R * ldc + Cc], v);
                    }
                } else if (MODE == 5) {
                    if (Cc < Nvalid) {
                        float* C = (float*)Cout;
                        C[(long)R * ldc + Cc] = v + bias[Cc];
                    }
                } else if (MODE == 6) {
                    float* C = (float*)Cout + (long)batch * sC;
                    C[(long)R * ldc + Cc] = v;
                    mymax = fmaxf(mymax, v);
                } else if (MODE == 7) {
                    float* C = (float*)Cout;
                    atomicAdd(&C[(long)R * ldc + Cc], v + (chunk == 0 ? bias[Cc] : 0.0f));
                }
            }
        }
    }
    if (MODE == 6) {
        for (int o = 32; o; o >>= 1) mymax = fmaxf(mymax, __shfl_xor(mymax, o));
        if (lane == 0) atomicMax((unsigned*)aux + batch, enc_f32(mymax));
    }
}

// ---------------- bucketize (searchsorted left) + mask ----------------
__global__ void bucket_kernel(const float* __restrict__ methy, int* __restrict__ idx, float* __restrict__ maskf) {
    const int n = blockIdx.x * 256 + threadIdx.x;
    if (n >= NTOK) return;
    const float u = methy[n];
    int cnt = (int)(u > -2.0f) + (int)(u > -1.0f);
    for (int k = 0; k < 100; k++) cnt += (int)(((float)k * 0.01f) < u);
    idx[n] = cnt;
    maskf[n] = (u != 0.0f) ? 1.0f : 0.0f;
}

// ---------------- embedding gather ----------------
__global__ void embed_kernel(const int* __restrict__ idx, const int* __restrict__ pos, const int* __restrict__ chromo,
                             const float* __restrict__ mt, const float* __restrict__ pt, const float* __restrict__ ct,
                             float* __restrict__ X) {
    const int n = blockIdx.x, t = threadIdx.x;  // 192 threads * float4
    const float4* a = (const float4*)(mt + (long)idx[n] * DIM);
    const float4* b = (const float4*)(pt + (long)pos[n] * DIM);
    const float4* c = (const float4*)(ct + (long)chromo[n] * DIM);
    float4 rr = a[t];
    const float4 u = b[t], w = c[t];
    rr.x += u.x + w.x; rr.y += u.y + w.y; rr.z += u.z + w.z; rr.w += u.w + w.w;
    ((float4*)(X + (long)n * DIM))[t] = rr;
}

// ---------------- layernorm -> bf16 ----------------
__global__ __launch_bounds__(256) void ln_kernel(const float* __restrict__ X,
        const float* __restrict__ g, const float* __restrict__ b, bf16_t* __restrict__ out) {
    const int n = blockIdx.x, t = threadIdx.x;
    const float* x = X + (long)n * DIM;
    const float v0 = x[t], v1 = x[t + 256], v2 = x[t + 512];
    float s = v0 + v1 + v2;
    float s2 = v0 * v0 + v1 * v1 + v2 * v2;
    __shared__ float smA[4], smB[4];
    for (int o = 32; o; o >>= 1) { s += __shfl_down(s, o); s2 += __shfl_down(s2, o); }
    if ((t & 63) == 0) { smA[t >> 6] = s; smB[t >> 6] = s2; }
    __syncthreads();
    s = smA[0] + smA[1] + smA[2] + smA[3];
    s2 = smB[0] + smB[1] + smB[2] + smB[3];
    const float mu = s * (1.0f / DIM);
    const float var = s2 * (1.0f / DIM) - mu * mu;
    const float rs = rsqrtf(var + 1e-5f);
    bf16_t* op = out + (long)n * DIM;
    op[t]       = (bf16_t)((v0 - mu) * rs * g[t]       + b[t]);
    op[t + 256] = (bf16_t)((v1 - mu) * rs * g[t + 256] + b[t + 256]);
    op[t + 512] = (bf16_t)((v2 - mu) * rs * g[t + 512] + b[t + 512]);
}

// ---------------- batched f32 [R,C] -> bf16 [C,R] transpose (guarded) ----------------
__global__ __launch_bounds__(256) void transpose_b(const float* __restrict__ in, long sIn, int R, int C,
                                                   bf16_t* __restrict__ out, long sOut, int ldo) {
    __shared__ float tile[32][33];
    in += (long)blockIdx.z * sIn;
    out += (long)blockIdx.z * sOut;
    const int c0 = blockIdx.x * 32, r0 = blockIdx.y * 32;
    const int t = threadIdx.x;
    const int tx = t & 31, ty = t >> 5;
    for (int i = 0; i < 32; i += 8) {
        const int rr = r0 + ty + i, cc = c0 + tx;
        tile[ty + i][tx] = (rr < R && cc < C) ? in[(long)rr * C + cc] : 0.0f;
    }
    __syncthreads();
    for (int i = 0; i < 32; i += 8) {
        const int cc = c0 + ty + i, rr = r0 + tx;
        if (cc < C && rr < R) out[(long)cc * ldo + rr] = (bf16_t)tile[tx][ty + i];
    }
}

// ---------------- generic f32 -> bf16 convert ----------------
__global__ void conv_kernel(const float* __restrict__ in, bf16_t* __restrict__ out, long n) {
    const long i = ((long)blockIdx.x * 256 + threadIdx.x) * 4;
    if (i >= n) return;
    const float4 v = *(const float4*)(in + i);
    bf16x4 o; o[0] = (bf16_t)v.x; o[1] = (bf16_t)v.y; o[2] = (bf16_t)v.z; o[3] = (bf16_t)v.w;
    *(bf16x4*)(out + i) = o;
}

// ---------------- qf = ratio*(exp(xd - diag - rowmax) + eps), bf16 ----------------
__global__ __launch_bounds__(256) void qf_kernel(const float* __restrict__ XD, const float* __restrict__ diagQ,
                                                 bf16_t* __restrict__ QF) {
    const int h = blockIdx.y;
    const int n = blockIdx.x * 4 + (threadIdx.x >> 6);
    const int lane = threadIdx.x & 63;
    const float4 v = *(const float4*)(XD + ((long)h * 4096 + n) * 256 + lane * 4);
    float mx = fmaxf(fmaxf(v.x, v.y), fmaxf(v.z, v.w));
    for (int o = 32; o; o >>= 1) mx = fmaxf(mx, __shfl_down(mx, o));
    mx = __shfl(mx, 0);
    const float dg = diagQ[h * 4096 + n] + mx;
    const float ratio = 0.0625f;
    bf16x4 ov;
    ov[0] = (bf16_t)(ratio * (__expf(v.x - dg) + 1e-4f));
    ov[1] = (bf16_t)(ratio * (__expf(v.y - dg) + 1e-4f));
    ov[2] = (bf16_t)(ratio * (__expf(v.z - dg) + 1e-4f));
    ov[3] = (bf16_t)(ratio * (__expf(v.w - dg) + 1e-4f));
    *(bf16x4*)(QF + ((long)h * 4096 + n) * 256 + lane * 4) = ov;
}

// ---------------- kf -> KFT[h][m][n] bf16 (+ksum atomics); decodes global max -------
__global__ __launch_bounds__(256) void kft_kernel(const float* __restrict__ XD, const float* __restrict__ diagK,
        const unsigned* __restrict__ kmxe, const float* __restrict__ maskf,
        bf16_t* __restrict__ KFT, float* __restrict__ ksum) {
    const int h = blockIdx.z, n0 = blockIdx.x * 128, m0 = blockIdx.y * 64;
    __shared__ bf16_t tile[64][136];
    const int t = threadIdx.x;
    const int ml = (t & 15) * 4, nl = t >> 4;
    const float km = dec_f32(kmxe[h]);
    const float ratio = 0.0625f;
    for (int i = 0; i < 128; i += 16) {
        const int n = n0 + nl + i;
        const float4 v = *(const float4*)(XD + ((long)h * 4096 + n) * 256 + m0 + ml);
        const float e = diagK[h * 4096 + n] + km;
        const float msk = maskf[n];
        tile[ml + 0][nl + i] = (bf16_t)(ratio * (__expf(v.x - e) + 1e-4f) * msk);
        tile[ml + 1][nl + i] = (bf16_t)(ratio * (__expf(v.y - e) + 1e-4f) * msk);
        tile[ml + 2][nl + i] = (bf16_t)(ratio * (__expf(v.z - e) + 1e-4f) * msk);
        tile[ml + 3][nl + i] = (bf16_t)(ratio * (__expf(v.w - e) + 1e-4f) * msk);
    }
    __syncthreads();
    const int nc = t & 127, mc = t >> 7;
    for (int i = 0; i < 64; i += 2) {
        const int m = i + mc;
        KFT[((long)h * 256 + m0 + m) * 4096 + n0 + nc] = tile[m][nc];
    }
    if (t < 64) {
        float s = 0.0f;
        for (int nn = 0; nn < 128; nn++) s += (float)tile[t][nn];
        atomicAdd(&ksum[h * 256 + m0 + t], s);
    }
}

// ---------------- d_inv = 1 / (qf . ksum) ----------------
__global__ __launch_bounds__(256) void denom_kernel(const bf16_t* __restrict__ QF, const float* __restrict__ ksum,
                                                    float* __restrict__ dinv) {
    const int h = blockIdx.y;
    const int n = blockIdx.x * 4 + (threadIdx.x >> 6);
    const int lane = threadIdx.x & 63;
    const bf16x4 qv = *(const bf16x4*)(QF + ((long)h * 4096 + n) * 256 + lane * 4);
    const float4 ks = *(const float4*)(ksum + h * 256 + lane * 4);
    float s = (float)qv[0] * ks.x + (float)qv[1] * ks.y + (float)qv[2] * ks.z + (float)qv[3] * ks.w;
    for (int o = 32; o; o >>= 1) s += __shfl_down(s, o);
    if (lane == 0) dinv[h * 4096 + n] = 1.0f / s;
}

// ---------------- ctx f32 [12][64][256] -> bf16 [12][128][256] ----------------
__global__ void ctxconv_kernel(const float* __restrict__ in, bf16_t* __restrict__ out) {
    const long i = ((long)blockIdx.x * 256 + threadIdx.x) * 4;
    const int h = (int)(i >> 14);
    const int rem = (int)(i & 16383);
    const float4 v = *(const float4*)(in + i);
    bf16x4 o; o[0] = (bf16_t)v.x; o[1] = (bf16_t)v.y; o[2] = (bf16_t)v.z; o[3] = (bf16_t)v.w;
    *(bf16x4*)(out + (long)h * 32768 + rem) = o;
}

extern "C" void kernel_launch(void* const* d_in, const int* in_sizes, int n_in,
                              void* d_out, int out_size, void* d_ws, size_t ws_size,
                              hipStream_t stream) {
    const float* methy        = (const float*)d_in[0];
    const int*   chromo       = (const int*)d_in[1];
    const int*   pos          = (const int*)d_in[2];
    const float* methy_table  = (const float*)d_in[3];
    const float* chromo_table = (const float*)d_in[4];
    const float* pos_table    = (const float*)d_in[5];
    const float* ln1_g = (const float*)d_in[6];
    const float* ln1_b = (const float*)d_in[7];
    const float* ln2_g = (const float*)d_in[8];
    const float* ln2_b = (const float*)d_in[9];
    const float* Wq = (const float*)d_in[10];
    const float* Wk = (const float*)d_in[11];
    const float* Wv = (const float*)d_in[12];
    const float* Wo = (const float*)d_in[13];
    const float* bo = (const float*)d_in[14];
    const float* W1 = (const float*)d_in[15];
    const float* b1 = (const float*)d_in[16];
    const float* W2 = (const float*)d_in[17];
    const float* b2 = (const float*)d_in[18];
    const float* proj = (const float*)d_in[19];
    const float* normf_g = (const float*)d_in[20];
    const float* normf_b = (const float*)d_in[21];
    const float* Wout = (const float*)d_in[22];
    const float* bout = (const float*)d_in[23];

    char* p = (char*)d_ws;
    auto alloc = [&](size_t bytes) { char* r = p; p += (bytes + 255) & ~(size_t)255; return r; };

    float*  X     = (float*)alloc((size_t)NTOK * DIM * 4);
    bf16_t* Hbf   = (bf16_t*)alloc((size_t)NTOK * DIM * 2);
    char*   BIG   = alloc((size_t)12 * 4096 * 256 * 4);   // XD(f32) / G(bf16)
    float*  XD    = (float*)BIG;
    bf16_t* G     = (bf16_t*)BIG;
    bf16_t* QKbf  = (bf16_t*)alloc((size_t)NTOK * 1536 * 2);  // reused as O (attn out)
    bf16_t* O     = QKbf;
    bf16_t* VT    = (bf16_t*)alloc((size_t)12 * 128 * 4096 * 2);
    bf16_t* QF    = (bf16_t*)alloc((size_t)12 * 4096 * 256 * 2);
    bf16_t* KFT   = (bf16_t*)alloc((size_t)12 * 256 * 4096 * 2);
    bf16_t* WqkvT = (bf16_t*)alloc((size_t)DEPTH * 2304 * 768 * 2);
    bf16_t* WoT   = (bf16_t*)alloc((size_t)DEPTH * 768 * 768 * 2);
    bf16_t* W1T   = (bf16_t*)alloc((size_t)DEPTH * 3072 * 768 * 2);
    bf16_t* W2T   = (bf16_t*)alloc((size_t)DEPTH * 768 * 3072 * 2);
    bf16_t* projbf= (bf16_t*)alloc((size_t)DEPTH * 256 * 64 * 2);
    bf16_t* WoutT = (bf16_t*)alloc((size_t)128 * 768 * 2);
    bf16_t* CTXbf = (bf16_t*)alloc((size_t)12 * 128 * 256 * 2);
    float*  diagQ = (float*)alloc((size_t)12 * 4096 * 4);
    float*  diagK = (float*)alloc((size_t)12 * 4096 * 4);
    float*  DINV  = (float*)alloc((size_t)12 * 4096 * 4);
    // contiguous zero region: CTXf + ksum + kmx (one memset per layer)
    const size_t ZB_CTX = (size_t)12 * 64 * 256 * 4;   // 786432
    const size_t ZB_KS  = (size_t)12 * 256 * 4;        // 12288
    char*   ZERO  = alloc(ZB_CTX + ZB_KS + 64);
    float*  CTXf  = (float*)ZERO;
    float*  ksum  = (float*)(ZERO + ZB_CTX);
    unsigned* kmx = (unsigned*)(ZERO + ZB_CTX + ZB_KS);
    int*    idxb  = (int*)alloc((size_t)4096 * 4);
    float*  maskf = (float*)alloc((size_t)4096 * 4);

    hipMemsetAsync(VT, 0, (size_t)12 * 128 * 4096 * 2, stream);      // pad rows 64..127 stay 0
    hipMemsetAsync(CTXbf, 0, (size_t)12 * 128 * 256 * 2, stream);    // pad rows 64..127 stay 0
    hipMemsetAsync(WoutT, 0, (size_t)128 * 768 * 2, stream);

    bucket_kernel<<<16, 256, 0, stream>>>(methy, idxb, maskf);
    embed_kernel<<<4096, 192, 0, stream>>>(idxb, pos, chromo, methy_table, pos_table, chromo_table, X);

    // ---- all weight prep upfront, batched over layers ----
    const long s768 = (long)768 * 768, sQKV = (long)2304 * 768, sFF = (long)3072 * 768;
    transpose_b<<<dim3(24, 24, DEPTH), 256, 0, stream>>>(Wq, s768, 768, 768, WqkvT, sQKV, 768);
    transpose_b<<<dim3(24, 24, DEPTH), 256, 0, stream>>>(Wk, s768, 768, 768, WqkvT + 768 * 768, sQKV, 768);
    transpose_b<<<dim3(24, 24, DEPTH), 256, 0, stream>>>(Wv, s768, 768, 768, WqkvT + 2 * 768 * 768, sQKV, 768);
    transpose_b<<<dim3(24, 24, DEPTH), 256, 0, stream>>>(Wo, s768, 768, 768, WoT, s768, 768);
    transpose_b<<<dim3(96, 24, DEPTH), 256, 0, stream>>>(W1, sFF, 768, 3072, W1T, sFF, 768);
    transpose_b<<<dim3(24, 96, DEPTH), 256, 0, stream>>>(W2, sFF, 3072, 768, W2T, sFF, 3072);
    transpose_b<<<dim3(4, 24, 1), 256, 0, stream>>>(Wout, 0, 768, VOUT, WoutT, 0, 768);
    conv_kernel<<<96, 256, 0, stream>>>(proj, projbf, (long)DEPTH * 256 * 64);

    for (int l = 0; l < DEPTH; l++) {
        const bf16_t* lWqkv = WqkvT + (long)l * sQKV;
        const bf16_t* lWo   = WoT + (long)l * s768;
        const bf16_t* lW1   = W1T + (long)l * sFF;
        const bf16_t* lW2   = W2T + (long)l * sFF;
        const bf16_t* lproj = projbf + (long)l * 256 * 64;

        hipMemsetAsync(ZERO, 0, ZB_CTX + ZB_KS + 64, stream);

        // LN1 -> fused QKV gemm (QKbf*dn + diag + VT)
        ln_kernel<<<4096, 256, 0, stream>>>(X, ln1_g + l * DIM, ln1_b + l * DIM, Hbf);
        gemm128<8><<<dim3(32, 18, 1), 256, 0, stream>>>(Hbf, 768, 0, lWqkv, 768, 0, QKbf, 1536, 0,
                                                        768, 1, diagQ, diagK, 0, 4096, 2304, VT);
        // q features
        gemm128<0><<<dim3(32, 2, 12), 256, 0, stream>>>(QKbf, 1536, 64, lproj, 64, 0, XD, 256, 1048576,
                                                        64, 1, nullptr, nullptr, 0, 4096, 256, nullptr);
        qf_kernel<<<dim3(1024, 12), 256, 0, stream>>>(XD, diagQ, QF);
        // k features + fused global per-head max
        gemm128<6><<<dim3(32, 2, 12), 256, 0, stream>>>(QKbf + 768, 1536, 64, lproj, 64, 0, XD, 256, 1048576,
                                                        64, 1, nullptr, nullptr, 0, 4096, 256, kmx);
        kft_kernel<<<dim3(32, 4, 12), 256, 0, stream>>>(XD, diagK, kmx, maskf, KFT, ksum);
        denom_kernel<<<dim3(1024, 12), 256, 0, stream>>>(QF, ksum, DINV);

        // ctx^T[h][d][m] = sum_n v[n][d] kf[n][m]   (split-K over n, atomic f32)
        gemm128<4><<<dim3(1, 2, 96), 256, 0, stream>>>(VT, 4096, (long)128 * 4096, KFT, 4096, (long)256 * 4096,
                                                       CTXf, 256, (long)64 * 256, 4096, 8,
                                                       nullptr, nullptr, 0, 64, 256, nullptr);
        ctxconv_kernel<<<192, 256, 0, stream>>>(CTXf, CTXbf);

        // o[n][h*64+d] = dinv[h][n] * sum_m qf[n][m] ctx^T[d][m]
        gemm128<3><<<dim3(32, 1, 12), 256, 0, stream>>>(QF, 256, (long)4096 * 256, CTXbf, 256, (long)128 * 256,
                                                        O, 768, 64, 256, 1, nullptr, DINV, 4096, 4096, 64, nullptr);
        // x += o @ Wo + bo   (split-K=2, atomic residual)
        gemm128<7><<<dim3(32, 6, 2), 256, 0, stream>>>(O, 768, 0, lWo, 768, 0, X, 768, 0,
                                                       768, 2, bo + l * DIM, nullptr, 0, 4096, 768, nullptr);
        // FF
        ln_kernel<<<4096, 256, 0, stream>>>(X, ln2_g + l * DIM, ln2_b + l * DIM, Hbf);
        gemm128<2><<<dim3(32, 24, 1), 256, 0, stream>>>(Hbf, 768, 0, lW1, 768, 0, G, 3072, 0,
                                                        768, 1, b1 + l * FFD, nullptr, 0, 4096, 3072, nullptr);
        gemm128<7><<<dim3(32, 6, 2), 256, 0, stream>>>(G, 3072, 0, lW2, 3072, 0, X, 768, 0,
                                                       3072, 2, b2 + l * DIM, nullptr, 0, 4096, 768, nullptr);
    }

    ln_kernel<<<4096, 256, 0, stream>>>(X, normf_g, normf_b, Hbf);
    gemm128<5><<<dim3(32, 1, 1), 256, 0, stream>>>(Hbf, 768, 0, WoutT, 768, 0, d_out, VOUT, 0,
                                                   768, 1, bout, nullptr, 0, 4096, VOUT, nullptr);
}

// Round 3
// 2069.035 us; speedup vs baseline: 1.1759x; 1.0432x over previous
//
#include <hip/hip_runtime.h>
#include <cstdint>

typedef __bf16 bf16_t;
typedef __bf16 bf16x8 __attribute__((ext_vector_type(8)));
typedef __bf16 bf16x4 __attribute__((ext_vector_type(4)));
typedef float f32x4 __attribute__((ext_vector_type(4)));
typedef _Float16 half_t;
typedef _Float16 half4 __attribute__((ext_vector_type(4)));

#define NTOK 4096
#define DIM 768
#define DEPTH 6
#define HEADS 12
#define FFD 3072
#define VOUT 102

// ---------------- async global->LDS (16B per lane, wave-uniform LDS base) -------------
__device__ __forceinline__ void gl_lds16(const void* g, void* l) {
    __builtin_amdgcn_global_load_lds(
        (__attribute__((address_space(1))) void*)(g),
        (__attribute__((address_space(3))) void*)(l), 16, 0, 0);
}

__device__ __forceinline__ unsigned enc_f32(float f) {
    unsigned u = __float_as_uint(f);
    return (u & 0x80000000u) ? ~u : (u | 0x80000000u);
}
__device__ __forceinline__ float dec_f32(unsigned e) {
    unsigned u = (e & 0x80000000u) ? (e & 0x7FFFFFFFu) : ~e;
    return __uint_as_float(u);
}

// ---------------- MFMA GEMM: C[M,N] = A[M,K] @ B^T[N,K]  (A,B bf16 row-major) ---------
// MODE 2: bf16 out = gelu(dot + bias[col])
// MODE 3: bf16 out = dot * rowscale[row], col < Nvalid
// MODE 4: atomicAdd f32 out += dot, row < Mvalid   (split-K)
// MODE 5: f32 out = dot + bias[col], col < Nvalid
// MODE 6: f16 out = dot; per-head global max -> atomicMax(aux[batch]) (encoded)
// MODE 7: atomicAdd f32 out += dot + (chunk==0 ? bias[col] : 0)   (split-K residual)
// MODE 8: fused QKV epilogue: q/k tiles -> QKbf(bf16*dn) + diagQ/diagK(bias/rowscale);
//         v tiles -> VT[h][d][n] via LDS transpose (aux)
template<int MODE>
__global__ __launch_bounds__(256, 2) void gemm128(
    const bf16_t* __restrict__ A, int lda, long sA,
    const bf16_t* __restrict__ B, int ldb, long sB,
    void* __restrict__ Cout, int ldc, long sC,
    int K, int nsplit,
    const float* __restrict__ bias,
    const float* __restrict__ rowscale, int sRS,
    int Mvalid, int Nvalid, void* __restrict__ aux)
{
    __shared__ __align__(16) bf16_t smem[16896];   // As(8192) + Bs(8192); reused 128x130 in MODE 8
    bf16_t* As = smem;
    bf16_t* Bs = smem + 8192;
    const int bz = blockIdx.z;
    const int batch = bz / nsplit, chunk = bz % nsplit;
    A += (long)batch * sA;
    B += (long)batch * sB;
    const int t = threadIdx.x;
    const int wave = t >> 6, lane = t & 63;
    const int wm = wave >> 1, wn = wave & 1;
    const int q = lane >> 4, r = lane & 15;
    const int tileM = blockIdx.x * 128, tileN = blockIdx.y * 128;
    const int Kc = K / nsplit;
    const int k0 = chunk * Kc;

    f32x4 acc[4][4] = {};

    for (int kt = 0; kt < Kc; kt += 64) {
        const int kb = k0 + kt;
#pragma unroll
        for (int i = 0; i < 4; i++) {
            const int c = i * 256 + t;
            const int row = c >> 3, kk = (c & 7) * 8;
            const bf16_t* ga = A + (long)(tileM + row) * lda + kb + kk;
            const bf16_t* gb = B + (long)(tileN + row) * ldb + kb + kk;
            char* la = (char*)As + (i * 256 + wave * 64) * 16;   // wave-uniform base
            char* lb = (char*)Bs + (i * 256 + wave * 64) * 16;
            gl_lds16(ga, la);
            gl_lds16(gb, lb);
        }
        __syncthreads();
#pragma unroll
        for (int kk = 0; kk < 64; kk += 32) {
            bf16x8 af[4], bfr[4];
#pragma unroll
            for (int i = 0; i < 4; i++)
                af[i] = *(const bf16x8*)(As + (wm * 64 + i * 16 + r) * 64 + kk + q * 8);
#pragma unroll
            for (int j = 0; j < 4; j++)
                bfr[j] = *(const bf16x8*)(Bs + (wn * 64 + j * 16 + r) * 64 + kk + q * 8);
#pragma unroll
            for (int i = 0; i < 4; i++)
#pragma unroll
                for (int j = 0; j < 4; j++)
                    acc[i][j] = __builtin_amdgcn_mfma_f32_16x16x32_bf16(af[i], bfr[j], acc[i][j], 0, 0, 0);
        }
        __syncthreads();
    }

    // C/D layout: col = lane&15 (=r), row-in-tile = q*4 + e
    if (MODE == 8) {
        const float dn = 0.3535533905932738f;  // 64^-0.25
        if (tileN < 1536) {
            bf16_t* QK = (bf16_t*)Cout;                 // [4096][1536]
            const int hcol = (tileN >> 6) + wn;         // 0..23 (q heads then k heads)
            float* dptr = (hcol < 12) ? ((float*)bias + (long)hcol * 4096)
                                      : ((float*)rowscale + (long)(hcol - 12) * 4096);
#pragma unroll
            for (int i = 0; i < 4; i++) {
#pragma unroll
                for (int e = 0; e < 4; e++) {
                    const int R = tileM + wm * 64 + i * 16 + q * 4 + e;
                    float ss = 0.0f;
#pragma unroll
                    for (int j = 0; j < 4; j++) {
                        const int Cc = tileN + wn * 64 + j * 16 + r;
                        const float v = acc[i][j][e] * dn;
                        QK[(long)R * 1536 + Cc] = (bf16_t)v;
                        ss += v * v;
                    }
                    for (int o = 8; o; o >>= 1) ss += __shfl_xor(ss, o);
                    if (r == 0) dptr[R] = 0.5f * ss;
                }
            }
        } else {
            bf16_t* VTp = (bf16_t*)aux;                 // [12][128][4096]
            bf16_t* tile = smem;                        // [128 cols][130]
#pragma unroll
            for (int i = 0; i < 4; i++)
#pragma unroll
                for (int j = 0; j < 4; j++)
#pragma unroll
                    for (int e = 0; e < 4; e++) {
                        const int row = wm * 64 + i * 16 + q * 4 + e;   // n-local
                        const int col = wn * 64 + j * 16 + r;           // d-local
                        tile[col * 130 + row] = (bf16_t)acc[i][j][e];
                    }
            __syncthreads();
            const int col = t >> 1, half = (t & 1) * 64;
            const int cg = tileN - 1536 + col;          // 0..767
            const int h = cg >> 6, d = cg & 63;
            bf16_t* dst = VTp + ((long)h * 128 + d) * 4096 + tileM + half;
            const bf16_t* src = tile + col * 130 + half;
#pragma unroll
            for (int u2 = 0; u2 < 64; u2 += 8)
                *(bf16x8*)(dst + u2) = *(const bf16x8*)(src + u2);
        }
        return;
    }

    float mymax = -3.0e38f;
#pragma unroll
    for (int i = 0; i < 4; i++) {
#pragma unroll
        for (int j = 0; j < 4; j++) {
#pragma unroll
            for (int e = 0; e < 4; e++) {
                const int R = tileM + wm * 64 + i * 16 + q * 4 + e;
                const int Cc = tileN + wn * 64 + j * 16 + r;
                const float v = acc[i][j][e];
                if (MODE == 2) {
                    const float x = v + bias[Cc];
                    const float z = 0.7978845608028654f * (x + 0.044715f * x * x * x);
                    const float th = 1.0f - 2.0f / (__expf(2.0f * z) + 1.0f);
                    bf16_t* Gp = (bf16_t*)Cout;
                    Gp[(long)R * ldc + Cc] = (bf16_t)(0.5f * x * (1.0f + th));
                } else if (MODE == 3) {
                    if (Cc < Nvalid) {
                        const float* rs = rowscale + (long)batch * sRS;
                        bf16_t* Ob = (bf16_t*)Cout + (long)batch * sC;
                        Ob[(long)R * ldc + Cc] = (bf16_t)(v * rs[R]);
                    }
                } else if (MODE == 4) {
                    if (R < Mvalid) {
                        float* C = (float*)Cout + (long)batch * sC;
                        atomicAdd(&C[(long)R * ldc + Cc], v);
                    }
                } else if (MODE == 5) {
                    if (Cc < Nvalid) {
                        float* C = (float*)Cout;
                        C[(long)R * ldc + Cc] = v + bias[Cc];
                    }
                } else if (MODE == 6) {
                    half_t* C = (half_t*)Cout + (long)batch * sC;
                    C[(long)R * ldc + Cc] = (half_t)v;
                    mymax = fmaxf(mymax, v);
                } else if (MODE == 7) {
                    float* C = (float*)Cout;
                    atomicAdd(&C[(long)R * ldc + Cc], v + (chunk == 0 ? bias[Cc] : 0.0f));
                }
            }
        }
    }
    if (MODE == 6) {
        for (int o = 32; o; o >>= 1) mymax = fmaxf(mymax, __shfl_xor(mymax, o));
        if (lane == 0) atomicMax((unsigned*)aux + batch, enc_f32(mymax));
    }
}

// ---------------- fused q-feature: xd GEMM (K=64, N=256 in-block) + rowmax + exp ------
// QF[h][n][m] = ratio*(exp(xd - diagQ - rowmax) + eps), xd = QKbf[n, h*64:..] @ proj^T
__global__ __launch_bounds__(256, 2) void qfeat_fused(
    const bf16_t* __restrict__ QKbf,      // [4096][1536], q half
    const bf16_t* __restrict__ projbf,    // [256][64]
    const float* __restrict__ diagQ,      // [12][4096]
    bf16_t* __restrict__ QF)              // [12][4096][256]
{
    __shared__ __align__(16) bf16_t As[128 * 64];    // 16 KB
    __shared__ __align__(16) bf16_t Bs[256 * 64];    // 32 KB
    __shared__ float rmax[2][128];
    const int h = blockIdx.y;
    const int tileM = blockIdx.x * 128;
    const int t = threadIdx.x, wave = t >> 6, lane = t & 63;
    const int wm = wave >> 1, wn = wave & 1;
    const int q = lane >> 4, r = lane & 15;
    const bf16_t* A = QKbf + h * 64;

#pragma unroll
    for (int i = 0; i < 4; i++) {
        const int c = i * 256 + t;
        const int row = c >> 3, kk = (c & 7) * 8;
        gl_lds16(A + (long)(tileM + row) * 1536 + kk, (char*)As + (i * 256 + wave * 64) * 16);
    }
#pragma unroll
    for (int i = 0; i < 8; i++) {
        const int c = i * 256 + t;
        gl_lds16(projbf + c * 8, (char*)Bs + (i * 256 + wave * 64) * 16);
    }
    __syncthreads();

    f32x4 acc[4][8] = {};
#pragma unroll
    for (int kk = 0; kk < 64; kk += 32) {
        bf16x8 af[4], bfr[8];
#pragma unroll
        for (int i = 0; i < 4; i++)
            af[i] = *(const bf16x8*)(As + (wm * 64 + i * 16 + r) * 64 + kk + q * 8);
#pragma unroll
        for (int j = 0; j < 8; j++)
            bfr[j] = *(const bf16x8*)(Bs + (wn * 128 + j * 16 + r) * 64 + kk + q * 8);
#pragma unroll
        for (int i = 0; i < 4; i++)
#pragma unroll
            for (int j = 0; j < 8; j++)
                acc[i][j] = __builtin_amdgcn_mfma_f32_16x16x32_bf16(af[i], bfr[j], acc[i][j], 0, 0, 0);
    }

    // per-row max: reduce over j (8 tiles) then over r (16 lanes), combine wn halves in LDS
#pragma unroll
    for (int i = 0; i < 4; i++) {
#pragma unroll
        for (int e = 0; e < 4; e++) {
            float m = acc[i][0][e];
#pragma unroll
            for (int j = 1; j < 8; j++) m = fmaxf(m, acc[i][j][e]);
            for (int o = 8; o; o >>= 1) m = fmaxf(m, __shfl_xor(m, o));
            if (r == 0) rmax[wn][wm * 64 + i * 16 + q * 4 + e] = m;
        }
    }
    __syncthreads();

    const float ratio = 0.0625f;
#pragma unroll
    for (int i = 0; i < 4; i++) {
#pragma unroll
        for (int e = 0; e < 4; e++) {
            const int rl = wm * 64 + i * 16 + q * 4 + e;
            const int R = tileM + rl;
            const float dg = diagQ[h * 4096 + R] + fmaxf(rmax[0][rl], rmax[1][rl]);
            bf16_t* op = QF + ((long)h * 4096 + R) * 256 + wn * 128 + r;
#pragma unroll
            for (int j = 0; j < 8; j++)
                op[j * 16] = (bf16_t)(ratio * (__expf(acc[i][j][e] - dg) + 1e-4f));
        }
    }
}

// ---------------- bucketize (searchsorted left) + mask ----------------
__global__ void bucket_kernel(const float* __restrict__ methy, int* __restrict__ idx, float* __restrict__ maskf) {
    const int n = blockIdx.x * 256 + threadIdx.x;
    if (n >= NTOK) return;
    const float u = methy[n];
    int cnt = (int)(u > -2.0f) + (int)(u > -1.0f);
    for (int k = 0; k < 100; k++) cnt += (int)(((float)k * 0.01f) < u);
    idx[n] = cnt;
    maskf[n] = (u != 0.0f) ? 1.0f : 0.0f;
}

// ---------------- embedding gather ----------------
__global__ void embed_kernel(const int* __restrict__ idx, const int* __restrict__ pos, const int* __restrict__ chromo,
                             const float* __restrict__ mt, const float* __restrict__ pt, const float* __restrict__ ct,
                             float* __restrict__ X) {
    const int n = blockIdx.x, t = threadIdx.x;  // 192 threads * float4
    const float4* a = (const float4*)(mt + (long)idx[n] * DIM);
    const float4* b = (const float4*)(pt + (long)pos[n] * DIM);
    const float4* c = (const float4*)(ct + (long)chromo[n] * DIM);
    float4 rr = a[t];
    const float4 u = b[t], w = c[t];
    rr.x += u.x + w.x; rr.y += u.y + w.y; rr.z += u.z + w.z; rr.w += u.w + w.w;
    ((float4*)(X + (long)n * DIM))[t] = rr;
}

// ---------------- layernorm -> bf16 ----------------
__global__ __launch_bounds__(256) void ln_kernel(const float* __restrict__ X,
        const float* __restrict__ g, const float* __restrict__ b, bf16_t* __restrict__ out) {
    const int n = blockIdx.x, t = threadIdx.x;
    const float* x = X + (long)n * DIM;
    const float v0 = x[t], v1 = x[t + 256], v2 = x[t + 512];
    float s = v0 + v1 + v2;
    float s2 = v0 * v0 + v1 * v1 + v2 * v2;
    __shared__ float smA[4], smB[4];
    for (int o = 32; o; o >>= 1) { s += __shfl_down(s, o); s2 += __shfl_down(s2, o); }
    if ((t & 63) == 0) { smA[t >> 6] = s; smB[t >> 6] = s2; }
    __syncthreads();
    s = smA[0] + smA[1] + smA[2] + smA[3];
    s2 = smB[0] + smB[1] + smB[2] + smB[3];
    const float mu = s * (1.0f / DIM);
    const float var = s2 * (1.0f / DIM) - mu * mu;
    const float rs = rsqrtf(var + 1e-5f);
    bf16_t* op = out + (long)n * DIM;
    op[t]       = (bf16_t)((v0 - mu) * rs * g[t]       + b[t]);
    op[t + 256] = (bf16_t)((v1 - mu) * rs * g[t + 256] + b[t + 256]);
    op[t + 512] = (bf16_t)((v2 - mu) * rs * g[t + 512] + b[t + 512]);
}

// ---------------- batched f32 [R,C] -> bf16 [C,R] transpose (guarded) ----------------
__global__ __launch_bounds__(256) void transpose_b(const float* __restrict__ in, long sIn, int R, int C,
                                                   bf16_t* __restrict__ out, long sOut, int ldo) {
    __shared__ float tile[32][33];
    in += (long)blockIdx.z * sIn;
    out += (long)blockIdx.z * sOut;
    const int c0 = blockIdx.x * 32, r0 = blockIdx.y * 32;
    const int t = threadIdx.x;
    const int tx = t & 31, ty = t >> 5;
    for (int i = 0; i < 32; i += 8) {
        const int rr = r0 + ty + i, cc = c0 + tx;
        tile[ty + i][tx] = (rr < R && cc < C) ? in[(long)rr * C + cc] : 0.0f;
    }
    __syncthreads();
    for (int i = 0; i < 32; i += 8) {
        const int cc = c0 + ty + i, rr = r0 + tx;
        if (cc < C && rr < R) out[(long)cc * ldo + rr] = (bf16_t)tile[tx][ty + i];
    }
}

// ---------------- generic f32 -> bf16 convert ----------------
__global__ void conv_kernel(const float* __restrict__ in, bf16_t* __restrict__ out, long n) {
    const long i = ((long)blockIdx.x * 256 + threadIdx.x) * 4;
    if (i >= n) return;
    const float4 v = *(const float4*)(in + i);
    bf16x4 o; o[0] = (bf16_t)v.x; o[1] = (bf16_t)v.y; o[2] = (bf16_t)v.z; o[3] = (bf16_t)v.w;
    *(bf16x4*)(out + i) = o;
}

// ---------------- kf -> KFT[h][m][n] bf16 (+ksum atomics); reads f16 xd ----------------
__global__ __launch_bounds__(256) void kft_kernel(const half_t* __restrict__ XDh, const float* __restrict__ diagK,
        const unsigned* __restrict__ kmxe, const float* __restrict__ maskf,
        bf16_t* __restrict__ KFT, float* __restrict__ ksum) {
    const int h = blockIdx.z, n0 = blockIdx.x * 128, m0 = blockIdx.y * 64;
    __shared__ bf16_t tile[64][136];
    const int t = threadIdx.x;
    const int ml = (t & 15) * 4, nl = t >> 4;
    const float km = dec_f32(kmxe[h]);
    const float ratio = 0.0625f;
    for (int i = 0; i < 128; i += 16) {
        const int n = n0 + nl + i;
        const half4 v = *(const half4*)(XDh + ((long)h * 4096 + n) * 256 + m0 + ml);
        const float e = diagK[h * 4096 + n] + km;
        const float msk = maskf[n];
        tile[ml + 0][nl + i] = (bf16_t)(ratio * (__expf((float)v[0] - e) + 1e-4f) * msk);
        tile[ml + 1][nl + i] = (bf16_t)(ratio * (__expf((float)v[1] - e) + 1e-4f) * msk);
        tile[ml + 2][nl + i] = (bf16_t)(ratio * (__expf((float)v[2] - e) + 1e-4f) * msk);
        tile[ml + 3][nl + i] = (bf16_t)(ratio * (__expf((float)v[3] - e) + 1e-4f) * msk);
    }
    __syncthreads();
    const int nc = t & 127, mc = t >> 7;
    for (int i = 0; i < 64; i += 2) {
        const int m = i + mc;
        KFT[((long)h * 256 + m0 + m) * 4096 + n0 + nc] = tile[m][nc];
    }
    if (t < 64) {
        float s = 0.0f;
        for (int nn = 0; nn < 128; nn++) s += (float)tile[t][nn];
        atomicAdd(&ksum[h * 256 + m0 + t], s);
    }
}

// ---------------- d_inv = 1 / (qf . ksum) ----------------
__global__ __launch_bounds__(256) void denom_kernel(const bf16_t* __restrict__ QF, const float* __restrict__ ksum,
                                                    float* __restrict__ dinv) {
    const int h = blockIdx.y;
    const int n = blockIdx.x * 4 + (threadIdx.x >> 6);
    const int lane = threadIdx.x & 63;
    const bf16x4 qv = *(const bf16x4*)(QF + ((long)h * 4096 + n) * 256 + lane * 4);
    const float4 ks = *(const float4*)(ksum + h * 256 + lane * 4);
    float s = (float)qv[0] * ks.x + (float)qv[1] * ks.y + (float)qv[2] * ks.z + (float)qv[3] * ks.w;
    for (int o = 32; o; o >>= 1) s += __shfl_down(s, o);
    if (lane == 0) dinv[h * 4096 + n] = 1.0f / s;
}

// ---------------- ctx f32 [12][64][256] -> bf16 [12][128][256] ----------------
__global__ void ctxconv_kernel(const float* __restrict__ in, bf16_t* __restrict__ out) {
    const long i = ((long)blockIdx.x * 256 + threadIdx.x) * 4;
    const int h = (int)(i >> 14);
    const int rem = (int)(i & 16383);
    const float4 v = *(const float4*)(in + i);
    bf16x4 o; o[0] = (bf16_t)v.x; o[1] = (bf16_t)v.y; o[2] = (bf16_t)v.z; o[3] = (bf16_t)v.w;
    *(bf16x4*)(out + (long)h * 32768 + rem) = o;
}

extern "C" void kernel_launch(void* const* d_in, const int* in_sizes, int n_in,
                              void* d_out, int out_size, void* d_ws, size_t ws_size,
                              hipStream_t stream) {
    const float* methy        = (const float*)d_in[0];
    const int*   chromo       = (const int*)d_in[1];
    const int*   pos          = (const int*)d_in[2];
    const float* methy_table  = (const float*)d_in[3];
    const float* chromo_table = (const float*)d_in[4];
    const float* pos_table    = (const float*)d_in[5];
    const float* ln1_g = (const float*)d_in[6];
    const float* ln1_b = (const float*)d_in[7];
    const float* ln2_g = (const float*)d_in[8];
    const float* ln2_b = (const float*)d_in[9];
    const float* Wq = (const float*)d_in[10];
    const float* Wk = (const float*)d_in[11];
    const float* Wv = (const float*)d_in[12];
    const float* Wo = (const float*)d_in[13];
    const float* bo = (const float*)d_in[14];
    const float* W1 = (const float*)d_in[15];
    const float* b1 = (const float*)d_in[16];
    const float* W2 = (const float*)d_in[17];
    const float* b2 = (const float*)d_in[18];
    const float* proj = (const float*)d_in[19];
    const float* normf_g = (const float*)d_in[20];
    const float* normf_b = (const float*)d_in[21];
    const float* Wout = (const float*)d_in[22];
    const float* bout = (const float*)d_in[23];

    char* p = (char*)d_ws;
    auto alloc = [&](size_t bytes) { char* r = p; p += (bytes + 255) & ~(size_t)255; return r; };

    float*  X     = (float*)alloc((size_t)NTOK * DIM * 4);
    bf16_t* Hbf   = (bf16_t*)alloc((size_t)NTOK * DIM * 2);
    char*   BIG   = alloc((size_t)12 * 4096 * 256 * 4);   // XDh(f16) / G(bf16)
    half_t* XDh   = (half_t*)BIG;
    bf16_t* G     = (bf16_t*)BIG;
    bf16_t* QKbf  = (bf16_t*)alloc((size_t)NTOK * 1536 * 2);  // reused as O (attn out)
    bf16_t* O     = QKbf;
    bf16_t* VT    = (bf16_t*)alloc((size_t)12 * 128 * 4096 * 2);
    bf16_t* QF    = (bf16_t*)alloc((size_t)12 * 4096 * 256 * 2);
    bf16_t* KFT   = (bf16_t*)alloc((size_t)12 * 256 * 4096 * 2);
    bf16_t* WqkvT = (bf16_t*)alloc((size_t)DEPTH * 2304 * 768 * 2);
    bf16_t* WoT   = (bf16_t*)alloc((size_t)DEPTH * 768 * 768 * 2);
    bf16_t* W1T   = (bf16_t*)alloc((size_t)DEPTH * 3072 * 768 * 2);
    bf16_t* W2T   = (bf16_t*)alloc((size_t)DEPTH * 768 * 3072 * 2);
    bf16_t* projbf= (bf16_t*)alloc((size_t)DEPTH * 256 * 64 * 2);
    bf16_t* WoutT = (bf16_t*)alloc((size_t)128 * 768 * 2);
    bf16_t* CTXbf = (bf16_t*)alloc((size_t)12 * 128 * 256 * 2);
    float*  diagQ = (float*)alloc((size_t)12 * 4096 * 4);
    float*  diagK = (float*)alloc((size_t)12 * 4096 * 4);
    float*  DINV  = (float*)alloc((size_t)12 * 4096 * 4);
    // contiguous zero region: CTXf + ksum + kmx (one memset per layer)
    const size_t ZB_CTX = (size_t)12 * 64 * 256 * 4;   // 786432
    const size_t ZB_KS  = (size_t)12 * 256 * 4;        // 12288
    char*   ZERO  = alloc(ZB_CTX + ZB_KS + 64);
    float*  CTXf  = (float*)ZERO;
    float*  ksum  = (float*)(ZERO + ZB_CTX);
    unsigned* kmx = (unsigned*)(ZERO + ZB_CTX + ZB_KS);
    int*    idxb  = (int*)alloc((size_t)4096 * 4);
    float*  maskf = (float*)alloc((size_t)4096 * 4);

    hipMemsetAsync(VT, 0, (size_t)12 * 128 * 4096 * 2, stream);      // pad rows 64..127 stay 0
    hipMemsetAsync(CTXbf, 0, (size_t)12 * 128 * 256 * 2, stream);    // pad rows 64..127 stay 0
    hipMemsetAsync(WoutT, 0, (size_t)128 * 768 * 2, stream);

    bucket_kernel<<<16, 256, 0, stream>>>(methy, idxb, maskf);
    embed_kernel<<<4096, 192, 0, stream>>>(idxb, pos, chromo, methy_table, pos_table, chromo_table, X);

    // ---- all weight prep upfront, batched over layers ----
    const long s768 = (long)768 * 768, sQKV = (long)2304 * 768, sFF = (long)3072 * 768;
    transpose_b<<<dim3(24, 24, DEPTH), 256, 0, stream>>>(Wq, s768, 768, 768, WqkvT, sQKV, 768);
    transpose_b<<<dim3(24, 24, DEPTH), 256, 0, stream>>>(Wk, s768, 768, 768, WqkvT + 768 * 768, sQKV, 768);
    transpose_b<<<dim3(24, 24, DEPTH), 256, 0, stream>>>(Wv, s768, 768, 768, WqkvT + 2 * 768 * 768, sQKV, 768);
    transpose_b<<<dim3(24, 24, DEPTH), 256, 0, stream>>>(Wo, s768, 768, 768, WoT, s768, 768);
    transpose_b<<<dim3(96, 24, DEPTH), 256, 0, stream>>>(W1, sFF, 768, 3072, W1T, sFF, 768);
    transpose_b<<<dim3(24, 96, DEPTH), 256, 0, stream>>>(W2, sFF, 3072, 768, W2T, sFF, 3072);
    transpose_b<<<dim3(4, 24, 1), 256, 0, stream>>>(Wout, 0, 768, VOUT, WoutT, 0, 768);
    conv_kernel<<<96, 256, 0, stream>>>(proj, projbf, (long)DEPTH * 256 * 64);

    for (int l = 0; l < DEPTH; l++) {
        const bf16_t* lWqkv = WqkvT + (long)l * sQKV;
        const bf16_t* lWo   = WoT + (long)l * s768;
        const bf16_t* lW1   = W1T + (long)l * sFF;
        const bf16_t* lW2   = W2T + (long)l * sFF;
        const bf16_t* lproj = projbf + (long)l * 256 * 64;

        hipMemsetAsync(ZERO, 0, ZB_CTX + ZB_KS + 64, stream);

        // LN1 -> fused QKV gemm (QKbf*dn + diag + VT)
        ln_kernel<<<4096, 256, 0, stream>>>(X, ln1_g + l * DIM, ln1_b + l * DIM, Hbf);
        gemm128<8><<<dim3(32, 18, 1), 256, 0, stream>>>(Hbf, 768, 0, lWqkv, 768, 0, QKbf, 1536, 0,
                                                        768, 1, diagQ, diagK, 0, 4096, 2304, VT);
        // q features: fully fused (xd + rowmax + exp -> QF)
        qfeat_fused<<<dim3(32, 12), 256, 0, stream>>>(QKbf, lproj, diagQ, QF);
        // k features (f16 xd) + fused global per-head max
        gemm128<6><<<dim3(32, 2, 12), 256, 0, stream>>>(QKbf + 768, 1536, 64, lproj, 64, 0, XDh, 256, 1048576,
                                                        64, 1, nullptr, nullptr, 0, 4096, 256, kmx);
        kft_kernel<<<dim3(32, 4, 12), 256, 0, stream>>>(XDh, diagK, kmx, maskf, KFT, ksum);
        denom_kernel<<<dim3(1024, 12), 256, 0, stream>>>(QF, ksum, DINV);

        // ctx^T[h][d][m] = sum_n v[n][d] kf[n][m]   (split-K over n, atomic f32)
        gemm128<4><<<dim3(1, 2, 96), 256, 0, stream>>>(VT, 4096, (long)128 * 4096, KFT, 4096, (long)256 * 4096,
                                                       CTXf, 256, (long)64 * 256, 4096, 8,
                                                       nullptr, nullptr, 0, 64, 256, nullptr);
        ctxconv_kernel<<<192, 256, 0, stream>>>(CTXf, CTXbf);

        // o[n][h*64+d] = dinv[h][n] * sum_m qf[n][m] ctx^T[d][m]
        gemm128<3><<<dim3(32, 1, 12), 256, 0, stream>>>(QF, 256, (long)4096 * 256, CTXbf, 256, (long)128 * 256,
                                                        O, 768, 64, 256, 1, nullptr, DINV, 4096, 4096, 64, nullptr);
        // x += o @ Wo + bo   (split-K=2, atomic residual)
        gemm128<7><<<dim3(32, 6, 2), 256, 0, stream>>>(O, 768, 0, lWo, 768, 0, X, 768, 0,
                                                       768, 2, bo + l * DIM, nullptr, 0, 4096, 768, nullptr);
        // FF
        ln_kernel<<<4096, 256, 0, stream>>>(X, ln2_g + l * DIM, ln2_b + l * DIM, Hbf);
        gemm128<2><<<dim3(32, 24, 1), 256, 0, stream>>>(Hbf, 768, 0, lW1, 768, 0, G, 3072, 0,
                                                        768, 1, b1 + l * FFD, nullptr, 0, 4096, 3072, nullptr);
        gemm128<7><<<dim3(32, 6, 2), 256, 0, stream>>>(G, 3072, 0, lW2, 3072, 0, X, 768, 0,
                                                       3072, 2, b2 + l * DIM, nullptr, 0, 4096, 768, nullptr);
    }

    ln_kernel<<<4096, 256, 0, stream>>>(X, normf_g, normf_b, Hbf);
    gemm128<5><<<dim3(32, 1, 1), 256, 0, stream>>>(Hbf, 768, 0, WoutT, 768, 0, d_out, VOUT, 0,
                                                   768, 1, bout, nullptr, 0, 4096, VOUT, nullptr);
}

// Round 4
// 1638.464 us; speedup vs baseline: 1.4849x; 1.2628x over previous
//
#include <hip/hip_runtime.h>
#include <cstdint>

typedef __bf16 bf16_t;
typedef __bf16 bf16x8 __attribute__((ext_vector_type(8)));
typedef __bf16 bf16x4 __attribute__((ext_vector_type(4)));
typedef float f32x4 __attribute__((ext_vector_type(4)));

#define NTOK 4096
#define DIM 768
#define DEPTH 6
#define HEADS 12
#define FFD 3072
#define VOUT 102

__device__ __forceinline__ void gl_lds16(const void* g, void* l) {
    __builtin_amdgcn_global_load_lds(
        (__attribute__((address_space(1))) void*)(g),
        (__attribute__((address_space(3))) void*)(l), 16, 0, 0);
}

__device__ __forceinline__ unsigned enc_f32(float f) {
    unsigned u = __float_as_uint(f);
    return (u & 0x80000000u) ? ~u : (u | 0x80000000u);
}
__device__ __forceinline__ float dec_f32(unsigned e) {
    unsigned u = (e & 0x80000000u) ? (e & 0x7FFFFFFFu) : ~e;
    return __uint_as_float(u);
}

// ---------------- MFMA GEMM: C[M,N] = A[M,K] @ B^T[N,K] ----------------
// MODE 2: bf16 out = gelu(dot + bias[col])
// MODE 4: atomicAdd f32 out += dot, row < Mvalid   (split-K)
// MODE 5: f32 out = dot + bias[col], col < Nvalid
// MODE 8: fused QKV epilogue (QKbf*dn + diag; V -> VT transpose)
// MODE 9: f32 plain store to Cout + chunk*sC   (split-K, no atomics)
template<int MODE>
__global__ __launch_bounds__(256, 2) void gemm128(
    const bf16_t* __restrict__ A, int lda, long sA,
    const bf16_t* __restrict__ B, int ldb, long sB,
    void* __restrict__ Cout, int ldc, long sC,
    int K, int nsplit,
    const float* __restrict__ bias,
    const float* __restrict__ rowscale,
    int Mvalid, int Nvalid, void* __restrict__ aux)
{
    __shared__ __align__(16) bf16_t smem[16896];
    bf16_t* As = smem;
    bf16_t* Bs = smem + 8192;
    const int bz = blockIdx.z;
    const int batch = bz / nsplit, chunk = bz % nsplit;
    A += (long)batch * sA;
    B += (long)batch * sB;
    const int t = threadIdx.x;
    const int wave = t >> 6, lane = t & 63;
    const int wm = wave >> 1, wn = wave & 1;
    const int q = lane >> 4, r = lane & 15;
    const int tileM = blockIdx.x * 128, tileN = blockIdx.y * 128;
    const int Kc = K / nsplit;
    const int k0 = chunk * Kc;

    f32x4 acc[4][4] = {};

    for (int kt = 0; kt < Kc; kt += 64) {
        const int kb = k0 + kt;
#pragma unroll
        for (int i = 0; i < 4; i++) {
            const int c = i * 256 + t;
            const int row = c >> 3, kk = (c & 7) * 8;
            gl_lds16(A + (long)(tileM + row) * lda + kb + kk, (char*)As + (i * 256 + wave * 64) * 16);
            gl_lds16(B + (long)(tileN + row) * ldb + kb + kk, (char*)Bs + (i * 256 + wave * 64) * 16);
        }
        __syncthreads();
#pragma unroll
        for (int kk = 0; kk < 64; kk += 32) {
            bf16x8 af[4], bfr[4];
#pragma unroll
            for (int i = 0; i < 4; i++)
                af[i] = *(const bf16x8*)(As + (wm * 64 + i * 16 + r) * 64 + kk + q * 8);
#pragma unroll
            for (int j = 0; j < 4; j++)
                bfr[j] = *(const bf16x8*)(Bs + (wn * 64 + j * 16 + r) * 64 + kk + q * 8);
#pragma unroll
            for (int i = 0; i < 4; i++)
#pragma unroll
                for (int j = 0; j < 4; j++)
                    acc[i][j] = __builtin_amdgcn_mfma_f32_16x16x32_bf16(af[i], bfr[j], acc[i][j], 0, 0, 0);
        }
        __syncthreads();
    }

    if (MODE == 8) {
        const float dn = 0.3535533905932738f;  // 64^-0.25
        if (tileN < 1536) {
            bf16_t* QK = (bf16_t*)Cout;                 // [4096][1536]
            const int hcol = (tileN >> 6) + wn;         // 0..23
            float* dptr = (hcol < 12) ? ((float*)bias + (long)hcol * 4096)
                                      : ((float*)rowscale + (long)(hcol - 12) * 4096);
#pragma unroll
            for (int i = 0; i < 4; i++) {
#pragma unroll
                for (int e = 0; e < 4; e++) {
                    const int R = tileM + wm * 64 + i * 16 + q * 4 + e;
                    float ss = 0.0f;
#pragma unroll
                    for (int j = 0; j < 4; j++) {
                        const int Cc = tileN + wn * 64 + j * 16 + r;
                        const float v = acc[i][j][e] * dn;
                        QK[(long)R * 1536 + Cc] = (bf16_t)v;
                        ss += v * v;
                    }
                    for (int o = 8; o; o >>= 1) ss += __shfl_xor(ss, o);
                    if (r == 0) dptr[R] = 0.5f * ss;
                }
            }
        } else {
            bf16_t* VTp = (bf16_t*)aux;                 // [12][128][4096]
            bf16_t* tile = smem;                        // [128 cols][130]
#pragma unroll
            for (int i = 0; i < 4; i++)
#pragma unroll
                for (int j = 0; j < 4; j++)
#pragma unroll
                    for (int e = 0; e < 4; e++) {
                        const int row = wm * 64 + i * 16 + q * 4 + e;
                        const int col = wn * 64 + j * 16 + r;
                        tile[col * 130 + row] = (bf16_t)acc[i][j][e];
                    }
            __syncthreads();
            const int col = t >> 1, half = (t & 1) * 64;
            const int cg = tileN - 1536 + col;
            const int h = cg >> 6, d = cg & 63;
            bf16_t* dst = VTp + ((long)h * 128 + d) * 4096 + tileM + half;
            const bf16_t* src = tile + col * 130 + half;
#pragma unroll
            for (int u2 = 0; u2 < 64; u2 += 8)
                *(bf16x8*)(dst + u2) = *(const bf16x8*)(src + u2);
        }
        return;
    }

#pragma unroll
    for (int i = 0; i < 4; i++) {
#pragma unroll
        for (int j = 0; j < 4; j++) {
#pragma unroll
            for (int e = 0; e < 4; e++) {
                const int R = tileM + wm * 64 + i * 16 + q * 4 + e;
                const int Cc = tileN + wn * 64 + j * 16 + r;
                const float v = acc[i][j][e];
                if (MODE == 2) {
                    const float x = v + bias[Cc];
                    const float z = 0.7978845608028654f * (x + 0.044715f * x * x * x);
                    const float th = 1.0f - 2.0f / (__expf(2.0f * z) + 1.0f);
                    bf16_t* Gp = (bf16_t*)Cout;
                    Gp[(long)R * ldc + Cc] = (bf16_t)(0.5f * x * (1.0f + th));
                } else if (MODE == 4) {
                    if (R < Mvalid) {
                        float* C = (float*)Cout + (long)batch * sC;
                        atomicAdd(&C[(long)R * ldc + Cc], v);
                    }
                } else if (MODE == 5) {
                    if (Cc < Nvalid) {
                        float* C = (float*)Cout;
                        C[(long)R * ldc + Cc] = v + bias[Cc];
                    }
                } else if (MODE == 9) {
                    float* C = (float*)Cout + (long)chunk * sC;
                    C[(long)R * ldc + Cc] = v;
                }
            }
        }
    }
}

// ---------------- combined q-features + k-global-max (grid y: 0..11 q, 12..23 k) -----
__global__ __launch_bounds__(256, 2) void qk_feat(
    const bf16_t* __restrict__ QKbf,      // [4096][1536]
    const bf16_t* __restrict__ projbf,    // [256][64]
    const float* __restrict__ diagQ,      // [12][4096]
    bf16_t* __restrict__ QF,              // [12][4096][256]
    unsigned* __restrict__ kmx)           // [12] encoded
{
    __shared__ __align__(16) bf16_t As[128 * 64];
    __shared__ __align__(16) bf16_t Bs[256 * 64];
    __shared__ float rmax[2][128];
    const int z = blockIdx.y;
    const bool isq = z < 12;
    const int h = isq ? z : z - 12;
    const int tileM = blockIdx.x * 128;
    const int t = threadIdx.x, wave = t >> 6, lane = t & 63;
    const int wm = wave >> 1, wn = wave & 1;
    const int q = lane >> 4, r = lane & 15;
    const bf16_t* A = QKbf + (isq ? 0 : 768) + h * 64;

#pragma unroll
    for (int i = 0; i < 4; i++) {
        const int c = i * 256 + t;
        gl_lds16(A + (long)(tileM + (c >> 3)) * 1536 + (c & 7) * 8, (char*)As + (i * 256 + wave * 64) * 16);
    }
#pragma unroll
    for (int i = 0; i < 8; i++) {
        const int c = i * 256 + t;
        gl_lds16(projbf + c * 8, (char*)Bs + (i * 256 + wave * 64) * 16);
    }
    __syncthreads();

    f32x4 acc[4][8] = {};
#pragma unroll
    for (int kk = 0; kk < 64; kk += 32) {
        bf16x8 af[4], bfr[8];
#pragma unroll
        for (int i = 0; i < 4; i++)
            af[i] = *(const bf16x8*)(As + (wm * 64 + i * 16 + r) * 64 + kk + q * 8);
#pragma unroll
        for (int j = 0; j < 8; j++)
            bfr[j] = *(const bf16x8*)(Bs + (wn * 128 + j * 16 + r) * 64 + kk + q * 8);
#pragma unroll
        for (int i = 0; i < 4; i++)
#pragma unroll
            for (int j = 0; j < 8; j++)
                acc[i][j] = __builtin_amdgcn_mfma_f32_16x16x32_bf16(af[i], bfr[j], acc[i][j], 0, 0, 0);
    }

    if (!isq) {   // k-side: block max -> atomicMax
        float m = -3.0e38f;
#pragma unroll
        for (int i = 0; i < 4; i++)
#pragma unroll
            for (int j = 0; j < 8; j++)
#pragma unroll
                for (int e = 0; e < 4; e++) m = fmaxf(m, acc[i][j][e]);
        for (int o = 32; o; o >>= 1) m = fmaxf(m, __shfl_xor(m, o));
        if (lane == 0) rmax[0][wave] = m;
        __syncthreads();
        if (t == 0) {
            m = fmaxf(fmaxf(rmax[0][0], rmax[0][1]), fmaxf(rmax[0][2], rmax[0][3]));
            atomicMax(kmx + h, enc_f32(m));
        }
        return;
    }

    // q-side: per-row max -> exp -> QF
#pragma unroll
    for (int i = 0; i < 4; i++) {
#pragma unroll
        for (int e = 0; e < 4; e++) {
            float m = acc[i][0][e];
#pragma unroll
            for (int j = 1; j < 8; j++) m = fmaxf(m, acc[i][j][e]);
            for (int o = 8; o; o >>= 1) m = fmaxf(m, __shfl_xor(m, o));
            if (r == 0) rmax[wn][wm * 64 + i * 16 + q * 4 + e] = m;
        }
    }
    __syncthreads();
    const float ratio = 0.0625f;
#pragma unroll
    for (int i = 0; i < 4; i++) {
#pragma unroll
        for (int e = 0; e < 4; e++) {
            const int rl = wm * 64 + i * 16 + q * 4 + e;
            const int R = tileM + rl;
            const float dg = diagQ[h * 4096 + R] + fmaxf(rmax[0][rl], rmax[1][rl]);
            bf16_t* op = QF + ((long)h * 4096 + R) * 256 + wn * 128 + r;
#pragma unroll
            for (int j = 0; j < 8; j++)
                op[j * 16] = (bf16_t)(ratio * (__expf(acc[i][j][e] - dg) + 1e-4f));
        }
    }
}

// ---------------- k-features: recompute xd, exp, LDS-transpose -> KFT[h][m][n] -------
__global__ __launch_bounds__(256, 2) void kfeat_fused(
    const bf16_t* __restrict__ QKbf,
    const bf16_t* __restrict__ projbf,
    const float* __restrict__ diagK,
    const unsigned* __restrict__ kmxe,
    const float* __restrict__ maskf,
    bf16_t* __restrict__ KFT)             // [12][256][4096]
{
    __shared__ __align__(16) bf16_t smem[24576];   // As(8192)+Bs(16384); reused as tile[128][136]
    bf16_t* As = smem;
    bf16_t* Bs = smem + 8192;
    const int h = blockIdx.y;
    const int tileM = blockIdx.x * 128;
    const int t = threadIdx.x, wave = t >> 6, lane = t & 63;
    const int wm = wave >> 1, wn = wave & 1;
    const int q = lane >> 4, r = lane & 15;
    const bf16_t* A = QKbf + 768 + h * 64;

#pragma unroll
    for (int i = 0; i < 4; i++) {
        const int c = i * 256 + t;
        gl_lds16(A + (long)(tileM + (c >> 3)) * 1536 + (c & 7) * 8, (char*)As + (i * 256 + wave * 64) * 16);
    }
#pragma unroll
    for (int i = 0; i < 8; i++) {
        const int c = i * 256 + t;
        gl_lds16(projbf + c * 8, (char*)Bs + (i * 256 + wave * 64) * 16);
    }
    __syncthreads();

    f32x4 acc[4][8] = {};
#pragma unroll
    for (int kk = 0; kk < 64; kk += 32) {
        bf16x8 af[4], bfr[8];
#pragma unroll
        for (int i = 0; i < 4; i++)
            af[i] = *(const bf16x8*)(As + (wm * 64 + i * 16 + r) * 64 + kk + q * 8);
#pragma unroll
        for (int j = 0; j < 8; j++)
            bfr[j] = *(const bf16x8*)(Bs + (wn * 128 + j * 16 + r) * 64 + kk + q * 8);
#pragma unroll
        for (int i = 0; i < 4; i++)
#pragma unroll
            for (int j = 0; j < 8; j++)
                acc[i][j] = __builtin_amdgcn_mfma_f32_16x16x32_bf16(af[i], bfr[j], acc[i][j], 0, 0, 0);
    }

    const float km = dec_f32(kmxe[h]);
    const float ratio = 0.0625f;
    float dg[4][4], mk[4][4];
#pragma unroll
    for (int i = 0; i < 4; i++)
#pragma unroll
        for (int e = 0; e < 4; e++) {
            const int R = tileM + wm * 64 + i * 16 + q * 4 + e;
            dg[i][e] = diagK[h * 4096 + R] + km;
            mk[i][e] = maskf[R];
        }

    bf16_t* tile = smem;   // [128 m][136]
#pragma unroll
    for (int mhalf = 0; mhalf < 2; mhalf++) {
        __syncthreads();
        if (wn == mhalf) {
#pragma unroll
            for (int i = 0; i < 4; i++)
#pragma unroll
                for (int j = 0; j < 8; j++)
#pragma unroll
                    for (int e = 0; e < 4; e++) {
                        const int rl = wm * 64 + i * 16 + q * 4 + e;
                        const int lc = j * 16 + r;
                        tile[lc * 136 + rl] =
                            (bf16_t)(ratio * (__expf(acc[i][j][e] - dg[i][e]) + 1e-4f) * mk[i][e]);
                    }
        }
        __syncthreads();
        const int m = t >> 1, nb = (t & 1) * 64;
        bf16_t* dst = KFT + ((long)h * 256 + mhalf * 128 + m) * 4096 + tileM + nb;
        const bf16_t* src = tile + m * 136 + nb;
#pragma unroll
        for (int c = 0; c < 64; c += 8)
            *(bf16x8*)(dst + c) = *(const bf16x8*)(src + c);
    }
}

// ---------------- PV fused: o = (QF @ ctx^T) * dinv, denom via ksum row ----------------
__global__ __launch_bounds__(256, 2) void pv_fused(
    const bf16_t* __restrict__ QF,        // [12][4096][256]
    const float* __restrict__ CTXf,       // [12][80][256]  rows 0..63 ctx, 64 ksum, 65..79 zero
    bf16_t* __restrict__ O)               // [4096][768]
{
    __shared__ __align__(16) bf16_t As[128 * 64];
    __shared__ __align__(16) bf16_t Bs[80 * 64];
    const int h = blockIdx.y;
    const int tileM = blockIdx.x * 128;
    const int t = threadIdx.x, wave = t >> 6, lane = t & 63;
    const int wm = wave >> 1, wn = wave & 1;
    const int q = lane >> 4, r = lane & 15;

    f32x4 acc[4][5] = {};
    for (int kt = 0; kt < 256; kt += 64) {
#pragma unroll
        for (int i = 0; i < 4; i++) {
            const int c = i * 256 + t;
            gl_lds16(QF + ((long)h * 4096 + tileM + (c >> 3)) * 256 + kt + (c & 7) * 8,
                     (char*)As + (i * 256 + wave * 64) * 16);
        }
#pragma unroll
        for (int u = 0; u < 5; u++) {
            const int idx = u * 256 + t;          // 1280 = 80*16
            const int row = idx >> 4, c4 = (idx & 15) * 4;
            const float4 v = *(const float4*)(CTXf + ((long)h * 80 + row) * 256 + kt + c4);
            bf16x4 o4; o4[0] = (bf16_t)v.x; o4[1] = (bf16_t)v.y; o4[2] = (bf16_t)v.z; o4[3] = (bf16_t)v.w;
            *(bf16x4*)(Bs + row * 64 + c4) = o4;
        }
        __syncthreads();
#pragma unroll
        for (int kk = 0; kk < 64; kk += 32) {
            bf16x8 af[4], bfr[5];
#pragma unroll
            for (int i = 0; i < 4; i++)
                af[i] = *(const bf16x8*)(As + (wm * 64 + i * 16 + r) * 64 + kk + q * 8);
#pragma unroll
            for (int j = 0; j < 5; j++)
                bfr[j] = *(const bf16x8*)(Bs + ((wn * 0 + j * 16 + r)) * 64 + kk + q * 8);
#pragma unroll
            for (int i = 0; i < 4; i++)
#pragma unroll
                for (int j = 0; j < 5; j++)
                    acc[i][j] = __builtin_amdgcn_mfma_f32_16x16x32_bf16(af[i], bfr[j], acc[i][j], 0, 0, 0);
        }
        __syncthreads();
    }
    // NOTE: both wn halves computed identical columns (wn unused in B) — harmless redundancy?
    // No: wn is unused, so waves wn=0/1 with same wm compute the same rows — we must restrict
    // writes to wn==0 OR split rows by wave differently. Rows: wm*64 covers 128 rows with 2 wm
    // values; wn duplicates. Only wn==0 writes.
    if (wn == 1) return;
#pragma unroll
    for (int i = 0; i < 4; i++) {
#pragma unroll
        for (int e = 0; e < 4; e++) {
            const int R = tileM + wm * 64 + i * 16 + q * 4 + e;
            float den = __shfl(acc[i][4][e], lane & 0x30);   // col 64 = ksum dot, at r==0
            const float dinv = 1.0f / den;
            bf16_t* op = O + (long)R * 768 + h * 64;
#pragma unroll
            for (int j = 0; j < 4; j++)
                op[j * 16 + r] = (bf16_t)(acc[i][j][e] * dinv);
        }
    }
}

// ---------------- bucketize + mask ----------------
__global__ void bucket_kernel(const float* __restrict__ methy, int* __restrict__ idx, float* __restrict__ maskf) {
    const int n = blockIdx.x * 256 + threadIdx.x;
    if (n >= NTOK) return;
    const float u = methy[n];
    int cnt = (int)(u > -2.0f) + (int)(u > -1.0f);
    for (int k = 0; k < 100; k++) cnt += (int)(((float)k * 0.01f) < u);
    idx[n] = cnt;
    maskf[n] = (u != 0.0f) ? 1.0f : 0.0f;
}

// ---------------- embedding gather ----------------
__global__ void embed_kernel(const int* __restrict__ idx, const int* __restrict__ pos, const int* __restrict__ chromo,
                             const float* __restrict__ mt, const float* __restrict__ pt, const float* __restrict__ ct,
                             float* __restrict__ X) {
    const int n = blockIdx.x, t = threadIdx.x;
    const float4* a = (const float4*)(mt + (long)idx[n] * DIM);
    const float4* b = (const float4*)(pt + (long)pos[n] * DIM);
    const float4* c = (const float4*)(ct + (long)chromo[n] * DIM);
    float4 rr = a[t];
    const float4 u = b[t], w = c[t];
    rr.x += u.x + w.x; rr.y += u.y + w.y; rr.z += u.z + w.z; rr.w += u.w + w.w;
    ((float4*)(X + (long)n * DIM))[t] = rr;
}

// ---------------- fused residual + layernorm -> bf16 (updates X in place) -------------
__global__ __launch_bounds__(256) void ln_fused(float* __restrict__ X,
        const float* __restrict__ D0, const float* __restrict__ D1, const float* __restrict__ rb,
        const float* __restrict__ g, const float* __restrict__ b, bf16_t* __restrict__ out) {
    const int n = blockIdx.x, t = threadIdx.x;
    float* x = X + (long)n * DIM;
    float v[3];
#pragma unroll
    for (int j = 0; j < 3; j++) {
        const int c = t + j * 256;
        float xv = x[c];
        if (D0) {
            xv += D0[(long)n * DIM + c] + D1[(long)n * DIM + c] + rb[c];
            x[c] = xv;
        }
        v[j] = xv;
    }
    float s = v[0] + v[1] + v[2];
    float s2 = v[0] * v[0] + v[1] * v[1] + v[2] * v[2];
    __shared__ float smA[4], smB[4];
    for (int o = 32; o; o >>= 1) { s += __shfl_down(s, o); s2 += __shfl_down(s2, o); }
    if ((t & 63) == 0) { smA[t >> 6] = s; smB[t >> 6] = s2; }
    __syncthreads();
    s = smA[0] + smA[1] + smA[2] + smA[3];
    s2 = smB[0] + smB[1] + smB[2] + smB[3];
    const float mu = s * (1.0f / DIM);
    const float var = s2 * (1.0f / DIM) - mu * mu;
    const float rs = rsqrtf(var + 1e-5f);
    bf16_t* op = out + (long)n * DIM;
#pragma unroll
    for (int j = 0; j < 3; j++) {
        const int c = t + j * 256;
        op[c] = (bf16_t)((v[j] - mu) * rs * g[c] + b[c]);
    }
}

// ---------------- batched transpose of the 4 square weights (Wq,Wk,Wv,Wo) ------------
__global__ __launch_bounds__(256) void transpose4(const float* __restrict__ Wq, const float* __restrict__ Wk,
        const float* __restrict__ Wv, const float* __restrict__ Wo,
        bf16_t* __restrict__ WqkvT, bf16_t* __restrict__ WoT) {
    __shared__ float tile[32][33];
    const int z = blockIdx.z, l = z >> 2, j = z & 3;
    const float* in = (j == 0 ? Wq : j == 1 ? Wk : j == 2 ? Wv : Wo) + (long)l * 768 * 768;
    bf16_t* out = (j < 3) ? WqkvT + (long)l * 2304 * 768 + (long)j * 768 * 768
                          : WoT + (long)l * 768 * 768;
    const int c0 = blockIdx.x * 32, r0 = blockIdx.y * 32;
    const int t = threadIdx.x, tx = t & 31, ty = t >> 5;
    for (int i = 0; i < 32; i += 8)
        tile[ty + i][tx] = in[(long)(r0 + ty + i) * 768 + c0 + tx];
    __syncthreads();
    for (int i = 0; i < 32; i += 8)
        out[(long)(c0 + ty + i) * 768 + r0 + tx] = (bf16_t)tile[tx][ty + i];
}

// ---------------- generic guarded transpose (W1, W2, Wout) ----------------
__global__ __launch_bounds__(256) void transpose_b(const float* __restrict__ in, long sIn, int R, int C,
                                                   bf16_t* __restrict__ out, long sOut, int ldo) {
    __shared__ float tile[32][33];
    in += (long)blockIdx.z * sIn;
    out += (long)blockIdx.z * sOut;
    const int c0 = blockIdx.x * 32, r0 = blockIdx.y * 32;
    const int t = threadIdx.x, tx = t & 31, ty = t >> 5;
    for (int i = 0; i < 32; i += 8) {
        const int rr = r0 + ty + i, cc = c0 + tx;
        tile[ty + i][tx] = (rr < R && cc < C) ? in[(long)rr * C + cc] : 0.0f;
    }
    __syncthreads();
    for (int i = 0; i < 32; i += 8) {
        const int cc = c0 + ty + i, rr = r0 + tx;
        if (cc < C && rr < R) out[(long)cc * ldo + rr] = (bf16_t)tile[tx][ty + i];
    }
}

__global__ void conv_kernel(const float* __restrict__ in, bf16_t* __restrict__ out, long n) {
    const long i = ((long)blockIdx.x * 256 + threadIdx.x) * 4;
    if (i >= n) return;
    const float4 v = *(const float4*)(in + i);
    bf16x4 o; o[0] = (bf16_t)v.x; o[1] = (bf16_t)v.y; o[2] = (bf16_t)v.z; o[3] = (bf16_t)v.w;
    *(bf16x4*)(out + i) = o;
}

__global__ void vtones_kernel(bf16_t* __restrict__ VT) {   // VT[h][64][n] = 1
    const int i = blockIdx.x * 256 + threadIdx.x;          // 12*4096
    const int h = i >> 12, n = i & 4095;
    VT[((long)h * 128 + 64) * 4096 + n] = (bf16_t)1.0f;
}

extern "C" void kernel_launch(void* const* d_in, const int* in_sizes, int n_in,
                              void* d_out, int out_size, void* d_ws, size_t ws_size,
                              hipStream_t stream) {
    const float* methy        = (const float*)d_in[0];
    const int*   chromo       = (const int*)d_in[1];
    const int*   pos          = (const int*)d_in[2];
    const float* methy_table  = (const float*)d_in[3];
    const float* chromo_table = (const float*)d_in[4];
    const float* pos_table    = (const float*)d_in[5];
    const float* ln1_g = (const float*)d_in[6];
    const float* ln1_b = (const float*)d_in[7];
    const float* ln2_g = (const float*)d_in[8];
    const float* ln2_b = (const float*)d_in[9];
    const float* Wq = (const float*)d_in[10];
    const float* Wk = (const float*)d_in[11];
    const float* Wv = (const float*)d_in[12];
    const float* Wo = (const float*)d_in[13];
    const float* bo = (const float*)d_in[14];
    const float* W1 = (const float*)d_in[15];
    const float* b1 = (const float*)d_in[16];
    const float* W2 = (const float*)d_in[17];
    const float* b2 = (const float*)d_in[18];
    const float* proj = (const float*)d_in[19];
    const float* normf_g = (const float*)d_in[20];
    const float* normf_b = (const float*)d_in[21];
    const float* Wout = (const float*)d_in[22];
    const float* bout = (const float*)d_in[23];

    char* p = (char*)d_ws;
    auto alloc = [&](size_t bytes) { char* r = p; p += (bytes + 255) & ~(size_t)255; return r; };

    float*  X     = (float*)alloc((size_t)NTOK * DIM * 4);
    bf16_t* Hbf   = (bf16_t*)alloc((size_t)NTOK * DIM * 2);
    bf16_t* G     = (bf16_t*)alloc((size_t)NTOK * FFD * 2);
    float*  D     = (float*)alloc((size_t)2 * NTOK * DIM * 4);   // split-K chunk buffers
    bf16_t* QKbf  = (bf16_t*)alloc((size_t)NTOK * 1536 * 2);     // reused as O
    bf16_t* O     = QKbf;
    bf16_t* VT    = (bf16_t*)alloc((size_t)12 * 128 * 4096 * 2);
    bf16_t* QF    = (bf16_t*)alloc((size_t)12 * 4096 * 256 * 2);
    bf16_t* KFT   = (bf16_t*)alloc((size_t)12 * 256 * 4096 * 2);
    bf16_t* WqkvT = (bf16_t*)alloc((size_t)DEPTH * 2304 * 768 * 2);
    bf16_t* WoT   = (bf16_t*)alloc((size_t)DEPTH * 768 * 768 * 2);
    bf16_t* W1T   = (bf16_t*)alloc((size_t)DEPTH * 3072 * 768 * 2);
    bf16_t* W2T   = (bf16_t*)alloc((size_t)DEPTH * 768 * 3072 * 2);
    bf16_t* projbf= (bf16_t*)alloc((size_t)DEPTH * 256 * 64 * 2);
    bf16_t* WoutT = (bf16_t*)alloc((size_t)128 * 768 * 2);
    float*  diagQ = (float*)alloc((size_t)12 * 4096 * 4);
    float*  diagK = (float*)alloc((size_t)12 * 4096 * 4);
    const size_t ZB_CTX = (size_t)12 * 80 * 256 * 4;             // 983040
    char*   ZERO  = alloc(ZB_CTX + 64);
    float*  CTXf  = (float*)ZERO;                                // [12][80][256]
    unsigned* kmx = (unsigned*)(ZERO + ZB_CTX);
    int*    idxb  = (int*)alloc((size_t)4096 * 4);
    float*  maskf = (float*)alloc((size_t)4096 * 4);

    hipMemsetAsync(VT, 0, (size_t)12 * 128 * 4096 * 2, stream);  // rows 65..127 stay 0
    hipMemsetAsync(WoutT, 0, (size_t)128 * 768 * 2, stream);
    vtones_kernel<<<192, 256, 0, stream>>>(VT);                   // row 64 = ones (persists)

    bucket_kernel<<<16, 256, 0, stream>>>(methy, idxb, maskf);
    embed_kernel<<<4096, 192, 0, stream>>>(idxb, pos, chromo, methy_table, pos_table, chromo_table, X);

    const long s768 = (long)768 * 768, sQKV = (long)2304 * 768, sFF = (long)3072 * 768;
    transpose4<<<dim3(24, 24, 4 * DEPTH), 256, 0, stream>>>(Wq, Wk, Wv, Wo, WqkvT, WoT);
    transpose_b<<<dim3(96, 24, DEPTH), 256, 0, stream>>>(W1, sFF, 768, 3072, W1T, sFF, 768);
    transpose_b<<<dim3(24, 96, DEPTH), 256, 0, stream>>>(W2, sFF, 3072, 768, W2T, sFF, 3072);
    transpose_b<<<dim3(4, 24, 1), 256, 0, stream>>>(Wout, 0, 768, VOUT, WoutT, 0, 768);
    conv_kernel<<<96, 256, 0, stream>>>(proj, projbf, (long)DEPTH * 256 * 64);

    float* D0 = D;
    float* D1 = D + (long)NTOK * DIM;

    for (int l = 0; l < DEPTH; l++) {
        const bf16_t* lWqkv = WqkvT + (long)l * sQKV;
        const bf16_t* lWo   = WoT + (long)l * s768;
        const bf16_t* lW1   = W1T + (long)l * sFF;
        const bf16_t* lW2   = W2T + (long)l * sFF;
        const bf16_t* lproj = projbf + (long)l * 256 * 64;

        hipMemsetAsync(ZERO, 0, ZB_CTX + 64, stream);

        // residual(prev FF2) + LN1
        if (l == 0)
            ln_fused<<<4096, 256, 0, stream>>>(X, nullptr, nullptr, nullptr,
                                               ln1_g, ln1_b, Hbf);
        else
            ln_fused<<<4096, 256, 0, stream>>>(X, D0, D1, b2 + (l - 1) * DIM,
                                               ln1_g + l * DIM, ln1_b + l * DIM, Hbf);

        gemm128<8><<<dim3(32, 18, 1), 256, 0, stream>>>(Hbf, 768, 0, lWqkv, 768, 0, QKbf, 1536, 0,
                                                        768, 1, diagQ, diagK, 4096, 2304, VT);
        qk_feat<<<dim3(32, 24), 256, 0, stream>>>(QKbf, lproj, diagQ, QF, kmx);
        kfeat_fused<<<dim3(32, 12), 256, 0, stream>>>(QKbf, lproj, diagK, kmx, maskf, KFT);

        // ctx (+ksum via ones row): rows 0..64 of CTXf
        gemm128<4><<<dim3(1, 2, 96), 256, 0, stream>>>(VT, 4096, (long)128 * 4096, KFT, 4096, (long)256 * 4096,
                                                       CTXf, 256, (long)80 * 256, 4096, 8,
                                                       nullptr, nullptr, 65, 256, nullptr);
        pv_fused<<<dim3(32, 12), 256, 0, stream>>>(QF, CTXf, O);

        // Wo (split-K plain stores into D0/D1)
        gemm128<9><<<dim3(32, 6, 2), 256, 0, stream>>>(O, 768, 0, lWo, 768, 0, D, 768, (long)NTOK * DIM,
                                                       768, 2, nullptr, nullptr, 4096, 768, nullptr);
        // residual(Wo) + LN2
        ln_fused<<<4096, 256, 0, stream>>>(X, D0, D1, bo + l * DIM,
                                           ln2_g + l * DIM, ln2_b + l * DIM, Hbf);
        gemm128<2><<<dim3(32, 24, 1), 256, 0, stream>>>(Hbf, 768, 0, lW1, 768, 0, G, 3072, 0,
                                                        768, 1, b1 + l * FFD, nullptr, 4096, 3072, nullptr);
        gemm128<9><<<dim3(32, 6, 2), 256, 0, stream>>>(G, 3072, 0, lW2, 3072, 0, D, 768, (long)NTOK * DIM,
                                                       3072, 2, nullptr, nullptr, 4096, 768, nullptr);
    }

    // final residual + LN + logits
    ln_fused<<<4096, 256, 0, stream>>>(X, D0, D1, b2 + (DEPTH - 1) * DIM, normf_g, normf_b, Hbf);
    gemm128<5><<<dim3(32, 1, 1), 256, 0, stream>>>(Hbf, 768, 0, WoutT, 768, 0, d_out, VOUT, 0,
                                                   768, 1, bout, nullptr, 4096, VOUT, nullptr);
}